// Round 3
// baseline (555.750 us; speedup 1.0000x reference)
//
#include <hip/hip_runtime.h>
#include <hip/hip_bf16.h>
#include <math.h>

typedef __attribute__((ext_vector_type(8))) short short8;
typedef __attribute__((ext_vector_type(4))) short short4_;
typedef __attribute__((ext_vector_type(4))) float f32x4;
typedef __attribute__((ext_vector_type(4))) unsigned int uint4_;

#define MFMA16(a, b, c) __builtin_amdgcn_mfma_f32_16x16x32_bf16((a), (b), (c), 0, 0, 0)

// fp32 -> bf16 round-to-nearest-even
__device__ __forceinline__ short f2bf(float f) {
  union { float f; unsigned u; } v; v.f = f;
  unsigned r = v.u + 0x7fffu + ((v.u >> 16) & 1u);
  return (short)(r >> 16);
}

// pack two fp32 -> 2x bf16 in one dword (v_cvt_pk_bf16_f32 when available)
__device__ __forceinline__ unsigned pk2bf(float a, float b) {
  union { __hip_bfloat162 h2; unsigned u; } cv;
  cv.h2 = __float22bfloat162_rn(float2{a, b});
  return cv.u;
}

__device__ __forceinline__ float fast_exp2(float x) {
#if __has_builtin(__builtin_amdgcn_exp2f)
  return __builtin_amdgcn_exp2f(x);
#else
  return __exp2f(x);
#endif
}

// scale(1/sqrt(256)) * log2(e), folded into Q values at the QKV GEMM epilogue
#define QSCALE 0.09016844005556f

// ---------------------------------------------------------------------------
// GroupNorm: one block per (batch, group). 16 ch x 1024 spatial = 16384 elems.
// ---------------------------------------------------------------------------
__global__ __launch_bounds__(256) void gn_kernel(const float* __restrict__ x,
                                                 const float* __restrict__ gamma,
                                                 const float* __restrict__ beta,
                                                 float* __restrict__ out) {
  const int blk = blockIdx.x;  // b*16 + g
  const int t = threadIdx.x;
  const size_t base = (size_t)blk * 16384;
  const float4* xp = (const float4*)(x + base);
  float s = 0.f, q = 0.f;
  float4 vals[16];
  for (int i = 0; i < 16; ++i) {
    float4 v = xp[t + i * 256];
    vals[i] = v;
    s += v.x + v.y + v.z + v.w;
    q += v.x * v.x + v.y * v.y + v.z * v.z + v.w * v.w;
  }
  __shared__ float rs[256], rq[256];
  rs[t] = s; rq[t] = q;
  __syncthreads();
  for (int o = 128; o > 0; o >>= 1) {
    if (t < o) { rs[t] += rs[t + o]; rq[t] += rq[t + o]; }
    __syncthreads();
  }
  __shared__ float sh_mu, sh_inv;
  if (t == 0) {
    float mu = rs[0] * (1.f / 16384.f);
    float var = rq[0] * (1.f / 16384.f) - mu * mu;
    sh_mu = mu;
    sh_inv = rsqrtf(var + 1e-5f);
  }
  __syncthreads();
  const float mu = sh_mu, inv = sh_inv;
  const int g = blk & 15;
  float4* op = (float4*)(out + base);
  for (int i = 0; i < 16; ++i) {
    int f = t + i * 256;
    int c = (g << 4) + (f >> 8);
    float ga = gamma[c], be = beta[c];
    float4 v = vals[i], y;
    y.x = (v.x - mu) * inv * ga + be;
    y.y = (v.y - mu) * inv * ga + be;
    y.z = (v.z - mu) * inv * ga + be;
    y.w = (v.w - mu) * inv * ga + be;
    op[f] = y;
  }
}

// ---------------------------------------------------------------------------
// QKV GEMM: computes qkv channels, writing:
//   Q -> [b, h, s, d] bf16, pre-scaled by QSCALE
//   K -> [b, h, s, d] bf16
//   V -> [b, h, d, s] bf16
// M=768, K=256, N=1024 per batch; 128x128 tile, 4 waves of 64x64.
// ---------------------------------------------------------------------------
__global__ __launch_bounds__(256) void gemm_qkv_kernel(const float* __restrict__ W,
                                                       const float* __restrict__ X,
                                                       short* __restrict__ Qb,
                                                       short* __restrict__ Kb,
                                                       short* __restrict__ Vb) {
  const int m0 = blockIdx.x * 128;
  const int n0 = blockIdx.y * 128;
  const int b = blockIdx.z;
  const int t = threadIdx.x;
  __shared__ short As[128][32];  // [m][k]
  __shared__ short Bs[128][32];  // [n][k]
  const int w = t >> 6, lane = t & 63, l15 = lane & 15, quad = lane >> 4;
  const int wm = (w >> 1) * 64, wn = (w & 1) * 64;
  const f32x4 z4 = {0.f, 0.f, 0.f, 0.f};
  f32x4 acc[4][4];
  for (int i = 0; i < 4; i++)
    for (int j = 0; j < 4; j++) acc[i][j] = z4;
  const int mm = t >> 1, half = (t & 1) * 16;
  const float* wrow = W + (size_t)(m0 + mm) * 256 + half;
  const size_t xbase = (size_t)b * 256 * 1024 + n0;

  for (int k0 = 0; k0 < 256; k0 += 32) {
    __syncthreads();
    {  // stage A (W slice) fp32 -> bf16
      const float* wp = wrow + k0;
      float4 a0 = *(const float4*)(wp);
      float4 a1 = *(const float4*)(wp + 4);
      float4 a2 = *(const float4*)(wp + 8);
      float4 a3 = *(const float4*)(wp + 12);
      short8 s0, s1;
      s0[0] = f2bf(a0.x); s0[1] = f2bf(a0.y); s0[2] = f2bf(a0.z); s0[3] = f2bf(a0.w);
      s0[4] = f2bf(a1.x); s0[5] = f2bf(a1.y); s0[6] = f2bf(a1.z); s0[7] = f2bf(a1.w);
      s1[0] = f2bf(a2.x); s1[1] = f2bf(a2.y); s1[2] = f2bf(a2.z); s1[3] = f2bf(a2.w);
      s1[4] = f2bf(a3.x); s1[5] = f2bf(a3.y); s1[6] = f2bf(a3.z); s1[7] = f2bf(a3.w);
      *(short8*)&As[mm][half] = s0;
      *(short8*)&As[mm][half + 8] = s1;
    }
    for (int p = 0; p < 4; ++p) {  // stage B transposed
      int kk = p * 8 + (t >> 5);
      int n4 = (t & 31) * 4;
      float4 xv = *(const float4*)(X + xbase + (size_t)(k0 + kk) * 1024 + n4);
      Bs[n4 + 0][kk] = f2bf(xv.x);
      Bs[n4 + 1][kk] = f2bf(xv.y);
      Bs[n4 + 2][kk] = f2bf(xv.z);
      Bs[n4 + 3][kk] = f2bf(xv.w);
    }
    __syncthreads();
    short8 af[4], bfr[4];
    for (int i = 0; i < 4; i++) af[i] = *(const short8*)&As[wm + i * 16 + l15][quad * 8];
    for (int j = 0; j < 4; j++) bfr[j] = *(const short8*)&Bs[wn + j * 16 + l15][quad * 8];
    for (int i = 0; i < 4; i++)
      for (int j = 0; j < 4; j++) acc[i][j] = MFMA16(af[i], bfr[j], acc[i][j]);
  }
  // Epilogue. Each i covers a 16-aligned channel block, which never crosses a
  // q/k/v or head boundary (all boundaries are multiples of 32) -> wave-uniform.
  for (int i = 0; i < 4; i++) {
    int mi = m0 + wm + i * 16;
    int h = mi / 96;
    int rr = mi - h * 96;  // multiple of 16
    if (rr < 64) {         // q or k: [b,h,s,d], 4 consecutive d per reg -> b64
      short* dst = (rr < 32) ? Qb : Kb;
      const float mul = (rr < 32) ? QSCALE : 1.0f;
      const int dbase = (rr & 31) + quad * 4;
      const size_t rowb = ((size_t)b * 8 + h) * 1024;
      for (int j = 0; j < 4; j++) {
        int n = n0 + wn + j * 16 + l15;
        short4_ sv;
        for (int r = 0; r < 4; r++) sv[r] = f2bf(acc[i][j][r] * mul);
        *(short4_*)(dst + (rowb + n) * 32 + dbase) = sv;
      }
    } else {  // v: [b,h,d,s]
      const int dv = (rr - 64) + quad * 4;
      const size_t base = (((size_t)b * 8 + h) * 32 + dv) * 1024;
      for (int j = 0; j < 4; j++) {
        int n = n0 + wn + j * 16 + l15;
        for (int r = 0; r < 4; r++) Vb[base + (size_t)r * 1024 + n] = f2bf(acc[i][j][r]);
      }
    }
  }
}

// ---------------------------------------------------------------------------
// Flash cross-attention, LDS-free, barrier-free.
// Grid (16 qtiles, 8 heads, 16 batch), 4 waves/block; wave owns 16 queries.
// S^T = MFMA(A=K, B=Q) -> lane holds P^T[sk=quad*4+r][sq=l15]; with a
// consistent k-slot permutation phi on both PV operands, two S^T fragments
// concatenate into one legal 16x16x32 A operand. p = exp2(score) (scale
// pre-folded into Q; no running max needed: |score*scale*log2e| << 127).
// ---------------------------------------------------------------------------
__global__ __launch_bounds__(256) void attn_kernel(const short* __restrict__ Qb,
                                                   const short* __restrict__ Kb,
                                                   const short* __restrict__ Vb,
                                                   short* __restrict__ AO) {
  const int qt = blockIdx.x, h = blockIdx.y, b = blockIdx.z;
  const int t = threadIdx.x;
  const int w = t >> 6, lane = t & 63, l15 = lane & 15, quad = lane >> 4;
  const size_t hb = (size_t)(b * 8 + h);
  const f32x4 z4 = {0.f, 0.f, 0.f, 0.f};
  // Q fragment (B operand): [n=sq=l15][k=d=quad*8+j]
  const short8 bq = *(const short8*)(Qb + (hb * 1024 + qt * 64 + w * 16 + l15) * 32 + quad * 8);
  const short* Kp = Kb + hb * 1024 * 32;            // [sk][32]
  const short* Vp = Vb + (hb * 32 + l15) * 1024;    // row dv = l15 (dvt adds 16 rows)

  f32x4 accO[2];
  accO[0] = z4;
  accO[1] = z4;
  float lsum = 0.f;

  for (int k0 = 0; k0 < 1024; k0 += 64) {
    // S^T: A = K fragment [m=sk=l15][k=d], 4 sk-blocks of 16
    f32x4 st[4];
    for (int j = 0; j < 4; j++) {
      const short8 ak = *(const short8*)(Kp + (size_t)(k0 + j * 16 + l15) * 32 + quad * 8);
      st[j] = MFMA16(ak, bq, z4);
    }
    // p = exp2(score); pack two j-fragments into one 16x16x32 A operand.
    // Slot map phi(q*8+o) = pr*32 + (o>>2)*16 + q*4 + (o&3); V side matches.
    union { short8 s; uint4_ u; } apv[2];
    for (int pr = 0; pr < 2; pr++) {
      for (int jj = 0; jj < 2; jj++) {
        const f32x4 sv = st[pr * 2 + jj];
        float p0 = fast_exp2(sv[0]);
        float p1 = fast_exp2(sv[1]);
        float p2 = fast_exp2(sv[2]);
        float p3 = fast_exp2(sv[3]);
        lsum += (p0 + p1) + (p2 + p3);
        apv[pr].u[jj * 2 + 0] = pk2bf(p0, p1);
        apv[pr].u[jj * 2 + 1] = pk2bf(p2, p3);
      }
    }
    // PV: B operand slot q*8+o -> V[dv=l15][k0 + pr*32 + (o>>2)*16 + q*4 + (o&3)]
    for (int pr = 0; pr < 2; pr++) {
      const short* vcol = Vp + k0 + pr * 32 + quad * 4;
      for (int dvt = 0; dvt < 2; dvt++) {
        union { short8 s; short4_ h[2]; } bv;
        bv.h[0] = *(const short4_*)(vcol + dvt * 16384);
        bv.h[1] = *(const short4_*)(vcol + dvt * 16384 + 16);
        accO[dvt] = MFMA16(apv[pr].s, bv.s, accO[dvt]);
      }
    }
  }
  // l(sq): every lane accumulated its own (quad,r,j) subset for sq=l15;
  // sum across the 4 quads, then broadcast to the C-layout rows.
  lsum += __shfl_xor(lsum, 16);
  lsum += __shfl_xor(lsum, 32);
  const int sqb = qt * 64 + w * 16;
  for (int r = 0; r < 4; r++) {
    float lr = __shfl(lsum, quad * 4 + r, 16);
    float inv = 1.0f / lr;
    int sq = sqb + quad * 4 + r;
    for (int dvt = 0; dvt < 2; dvt++)
      AO[((size_t)b * 256 + h * 32 + dvt * 16 + l15) * 1024 + sq] = f2bf(accO[dvt][r] * inv);
  }
}

// ---------------------------------------------------------------------------
// Output GEMM: out_f32[b,m,n] = sum_k W[m,k]*X_bf16[b,k,n] + bias[m] + resid
// ---------------------------------------------------------------------------
__global__ __launch_bounds__(256) void gemm_out_kernel(const float* __restrict__ W,
                                                       const short* __restrict__ X,
                                                       const float* __restrict__ bias,
                                                       const float* __restrict__ resid,
                                                       float* __restrict__ out) {
  const int m0 = blockIdx.x * 128;
  const int n0 = blockIdx.y * 128;
  const int b = blockIdx.z;
  const int t = threadIdx.x;
  __shared__ short As[128][32];
  __shared__ short Bs[128][32];
  const int w = t >> 6, lane = t & 63, l15 = lane & 15, quad = lane >> 4;
  const int wm = (w >> 1) * 64, wn = (w & 1) * 64;
  const f32x4 z4 = {0.f, 0.f, 0.f, 0.f};
  f32x4 acc[4][4];
  for (int i = 0; i < 4; i++)
    for (int j = 0; j < 4; j++) acc[i][j] = z4;
  const int mm = t >> 1, half = (t & 1) * 16;
  const float* wrow = W + (size_t)(m0 + mm) * 256 + half;
  const size_t xbase = (size_t)b * 256 * 1024 + n0;

  for (int k0 = 0; k0 < 256; k0 += 32) {
    __syncthreads();
    {
      const float* wp = wrow + k0;
      float4 a0 = *(const float4*)(wp);
      float4 a1 = *(const float4*)(wp + 4);
      float4 a2 = *(const float4*)(wp + 8);
      float4 a3 = *(const float4*)(wp + 12);
      short8 s0, s1;
      s0[0] = f2bf(a0.x); s0[1] = f2bf(a0.y); s0[2] = f2bf(a0.z); s0[3] = f2bf(a0.w);
      s0[4] = f2bf(a1.x); s0[5] = f2bf(a1.y); s0[6] = f2bf(a1.z); s0[7] = f2bf(a1.w);
      s1[0] = f2bf(a2.x); s1[1] = f2bf(a2.y); s1[2] = f2bf(a2.z); s1[3] = f2bf(a2.w);
      s1[4] = f2bf(a3.x); s1[5] = f2bf(a3.y); s1[6] = f2bf(a3.z); s1[7] = f2bf(a3.w);
      *(short8*)&As[mm][half] = s0;
      *(short8*)&As[mm][half + 8] = s1;
    }
    for (int p = 0; p < 4; ++p) {
      int kk = p * 8 + (t >> 5);
      int n4 = (t & 31) * 4;
      short4_ xv = *(const short4_*)(X + xbase + (size_t)(k0 + kk) * 1024 + n4);
      Bs[n4 + 0][kk] = xv[0];
      Bs[n4 + 1][kk] = xv[1];
      Bs[n4 + 2][kk] = xv[2];
      Bs[n4 + 3][kk] = xv[3];
    }
    __syncthreads();
    short8 af[4], bfr[4];
    for (int i = 0; i < 4; i++) af[i] = *(const short8*)&As[wm + i * 16 + l15][quad * 8];
    for (int j = 0; j < 4; j++) bfr[j] = *(const short8*)&Bs[wn + j * 16 + l15][quad * 8];
    for (int i = 0; i < 4; i++)
      for (int j = 0; j < 4; j++) acc[i][j] = MFMA16(af[i], bfr[j], acc[i][j]);
  }
  for (int i = 0; i < 4; i++)
    for (int j = 0; j < 4; j++) {
      int m = m0 + wm + i * 16 + quad * 4;
      int n = n0 + wn + j * 16 + l15;
      size_t off = ((size_t)b * 256 + m) * 1024 + n;
      for (int r = 0; r < 4; r++)
        out[off + (size_t)r * 1024] = acc[i][j][r] + bias[m + r] + resid[off + (size_t)r * 1024];
    }
}

// ---------------------------------------------------------------------------
extern "C" void kernel_launch(void* const* d_in, const int* in_sizes, int n_in,
                              void* d_out, int out_size, void* d_ws, size_t ws_size,
                              hipStream_t stream) {
  const float* xA = (const float*)d_in[0];
  const float* xB = (const float*)d_in[1];
  const float* gA = (const float*)d_in[2];
  const float* bA = (const float*)d_in[3];
  const float* gB = (const float*)d_in[4];
  const float* bB = (const float*)d_in[5];
  const float* WqkvA = (const float*)d_in[6];
  const float* WqkvB = (const float*)d_in[7];
  const float* WoutA = (const float*)d_in[8];
  const float* boutA = (const float*)d_in[9];
  const float* WoutB = (const float*)d_in[10];
  const float* boutB = (const float*)d_in[11];
  float* out = (float*)d_out;
  char* ws = (char*)d_ws;
  // workspace layout (96 MB total)
  float* nA  = (float*)(ws);                  // 16 MB fp32 norm A
  float* nB  = (float*)(ws + 16777216);       // 16 MB fp32 norm B
  short* QbA = (short*)(ws + 33554432);       // 8 MB bf16 Q_A [b,h,s,d] (pre-scaled)
  short* KbA = (short*)(ws + 41943040);       // 8 MB bf16 K_A [b,h,s,d]
  short* VbA = (short*)(ws + 50331648);       // 8 MB bf16 V_A [b,h,d,s]
  short* QbB = (short*)(ws + 58720256);
  short* KbB = (short*)(ws + 67108864);
  short* VbB = (short*)(ws + 75497472);
  short* aoA = (short*)(ws + 83886080);       // 8 MB bf16 attn-out A [b,c,s]
  short* aoB = (short*)(ws + 92274688);       // 8 MB bf16 attn-out B

  gn_kernel<<<256, 256, 0, stream>>>(xA, gA, bA, nA);
  gn_kernel<<<256, 256, 0, stream>>>(xB, gB, bB, nB);
  gemm_qkv_kernel<<<dim3(6, 8, 16), 256, 0, stream>>>(WqkvA, nA, QbA, KbA, VbA);
  gemm_qkv_kernel<<<dim3(6, 8, 16), 256, 0, stream>>>(WqkvB, nB, QbB, KbB, VbB);
  // branch A output: attn(qB -> kA,vA); branch B: attn(qA -> kB,vB)
  attn_kernel<<<dim3(16, 8, 16), 256, 0, stream>>>(QbB, KbA, VbA, aoA);
  attn_kernel<<<dim3(16, 8, 16), 256, 0, stream>>>(QbA, KbB, VbB, aoB);
  gemm_out_kernel<<<dim3(2, 8, 16), 256, 0, stream>>>(WoutA, aoA, boutA, nA, out);
  gemm_out_kernel<<<dim3(2, 8, 16), 256, 0, stream>>>(WoutB, aoB, boutB, nB, out + 4194304);
}

// Round 4
// 347.802 us; speedup vs baseline: 1.5979x; 1.5979x over previous
//
#include <hip/hip_runtime.h>
#include <hip/hip_bf16.h>
#include <math.h>

typedef __attribute__((ext_vector_type(8))) short short8;
typedef __attribute__((ext_vector_type(4))) short short4_;
typedef __attribute__((ext_vector_type(4))) float f32x4;
typedef __attribute__((ext_vector_type(4))) unsigned int uint4_;

#define MFMA16(a, b, c) __builtin_amdgcn_mfma_f32_16x16x32_bf16((a), (b), (c), 0, 0, 0)

// fp32 -> bf16 round-to-nearest-even
__device__ __forceinline__ short f2bf(float f) {
  union { float f; unsigned u; } v; v.f = f;
  unsigned r = v.u + 0x7fffu + ((v.u >> 16) & 1u);
  return (short)(r >> 16);
}

// pack two fp32 -> 2x bf16 in one dword (v_cvt_pk_bf16_f32 when available)
__device__ __forceinline__ unsigned pk2bf(float a, float b) {
  union { __hip_bfloat162 h2; unsigned u; } cv;
  cv.h2 = __float22bfloat162_rn(float2{a, b});
  return cv.u;
}

__device__ __forceinline__ float fast_exp2(float x) {
#if __has_builtin(__builtin_amdgcn_exp2f)
  return __builtin_amdgcn_exp2f(x);
#else
  return __exp2f(x);
#endif
}

// async global -> LDS, 16 B per lane; lptr must be wave-uniform
__device__ __forceinline__ void load_lds16(const void* g, void* l) {
  __builtin_amdgcn_global_load_lds((const __attribute__((address_space(1))) void*)g,
                                   (__attribute__((address_space(3))) void*)l, 16, 0, 0);
}

// scale(1/sqrt(256)) * log2(e), folded into Q values at the QKV GEMM epilogue
#define QSCALE 0.09016844005556f

// ---------------------------------------------------------------------------
// GroupNorm: one block per (batch, group). 16 ch x 1024 spatial = 16384 elems.
// ---------------------------------------------------------------------------
__global__ __launch_bounds__(256) void gn_kernel(const float* __restrict__ x,
                                                 const float* __restrict__ gamma,
                                                 const float* __restrict__ beta,
                                                 float* __restrict__ out) {
  const int blk = blockIdx.x;  // b*16 + g
  const int t = threadIdx.x;
  const size_t base = (size_t)blk * 16384;
  const float4* xp = (const float4*)(x + base);
  float s = 0.f, q = 0.f;
  float4 vals[16];
  for (int i = 0; i < 16; ++i) {
    float4 v = xp[t + i * 256];
    vals[i] = v;
    s += v.x + v.y + v.z + v.w;
    q += v.x * v.x + v.y * v.y + v.z * v.z + v.w * v.w;
  }
  __shared__ float rs[256], rq[256];
  rs[t] = s; rq[t] = q;
  __syncthreads();
  for (int o = 128; o > 0; o >>= 1) {
    if (t < o) { rs[t] += rs[t + o]; rq[t] += rq[t + o]; }
    __syncthreads();
  }
  __shared__ float sh_mu, sh_inv;
  if (t == 0) {
    float mu = rs[0] * (1.f / 16384.f);
    float var = rq[0] * (1.f / 16384.f) - mu * mu;
    sh_mu = mu;
    sh_inv = rsqrtf(var + 1e-5f);
  }
  __syncthreads();
  const float mu = sh_mu, inv = sh_inv;
  const int g = blk & 15;
  float4* op = (float4*)(out + base);
  for (int i = 0; i < 16; ++i) {
    int f = t + i * 256;
    int c = (g << 4) + (f >> 8);
    float ga = gamma[c], be = beta[c];
    float4 v = vals[i], y;
    y.x = (v.x - mu) * inv * ga + be;
    y.y = (v.y - mu) * inv * ga + be;
    y.z = (v.z - mu) * inv * ga + be;
    y.w = (v.w - mu) * inv * ga + be;
    op[f] = y;
  }
}

// ---------------------------------------------------------------------------
// QKV GEMM: computes qkv channels, writing:
//   Q -> [b, h, s, d] bf16, pre-scaled by QSCALE
//   K -> [b, h, s, d] bf16
//   V -> [b, h, d, s] bf16
// M=768, K=256, N=1024 per batch; 128x128 tile, 4 waves of 64x64.
// ---------------------------------------------------------------------------
__global__ __launch_bounds__(256) void gemm_qkv_kernel(const float* __restrict__ W,
                                                       const float* __restrict__ X,
                                                       short* __restrict__ Qb,
                                                       short* __restrict__ Kb,
                                                       short* __restrict__ Vb) {
  const int m0 = blockIdx.x * 128;
  const int n0 = blockIdx.y * 128;
  const int b = blockIdx.z;
  const int t = threadIdx.x;
  __shared__ short As[128][32];  // [m][k]
  __shared__ short Bs[128][32];  // [n][k]
  const int w = t >> 6, lane = t & 63, l15 = lane & 15, quad = lane >> 4;
  const int wm = (w >> 1) * 64, wn = (w & 1) * 64;
  const f32x4 z4 = {0.f, 0.f, 0.f, 0.f};
  f32x4 acc[4][4];
  for (int i = 0; i < 4; i++)
    for (int j = 0; j < 4; j++) acc[i][j] = z4;
  const int mm = t >> 1, half = (t & 1) * 16;
  const float* wrow = W + (size_t)(m0 + mm) * 256 + half;
  const size_t xbase = (size_t)b * 256 * 1024 + n0;

  for (int k0 = 0; k0 < 256; k0 += 32) {
    __syncthreads();
    {  // stage A (W slice) fp32 -> bf16
      const float* wp = wrow + k0;
      float4 a0 = *(const float4*)(wp);
      float4 a1 = *(const float4*)(wp + 4);
      float4 a2 = *(const float4*)(wp + 8);
      float4 a3 = *(const float4*)(wp + 12);
      short8 s0, s1;
      s0[0] = f2bf(a0.x); s0[1] = f2bf(a0.y); s0[2] = f2bf(a0.z); s0[3] = f2bf(a0.w);
      s0[4] = f2bf(a1.x); s0[5] = f2bf(a1.y); s0[6] = f2bf(a1.z); s0[7] = f2bf(a1.w);
      s1[0] = f2bf(a2.x); s1[1] = f2bf(a2.y); s1[2] = f2bf(a2.z); s1[3] = f2bf(a2.w);
      s1[4] = f2bf(a3.x); s1[5] = f2bf(a3.y); s1[6] = f2bf(a3.z); s1[7] = f2bf(a3.w);
      *(short8*)&As[mm][half] = s0;
      *(short8*)&As[mm][half + 8] = s1;
    }
    for (int p = 0; p < 4; ++p) {  // stage B transposed
      int kk = p * 8 + (t >> 5);
      int n4 = (t & 31) * 4;
      float4 xv = *(const float4*)(X + xbase + (size_t)(k0 + kk) * 1024 + n4);
      Bs[n4 + 0][kk] = f2bf(xv.x);
      Bs[n4 + 1][kk] = f2bf(xv.y);
      Bs[n4 + 2][kk] = f2bf(xv.z);
      Bs[n4 + 3][kk] = f2bf(xv.w);
    }
    __syncthreads();
    short8 af[4], bfr[4];
    for (int i = 0; i < 4; i++) af[i] = *(const short8*)&As[wm + i * 16 + l15][quad * 8];
    for (int j = 0; j < 4; j++) bfr[j] = *(const short8*)&Bs[wn + j * 16 + l15][quad * 8];
    for (int i = 0; i < 4; i++)
      for (int j = 0; j < 4; j++) acc[i][j] = MFMA16(af[i], bfr[j], acc[i][j]);
  }
  // Epilogue. Each i covers a 16-aligned channel block, which never crosses a
  // q/k/v or head boundary (all boundaries are multiples of 32) -> wave-uniform.
  for (int i = 0; i < 4; i++) {
    int mi = m0 + wm + i * 16;
    int h = mi / 96;
    int rr = mi - h * 96;  // multiple of 16
    if (rr < 64) {         // q or k: [b,h,s,d], 4 consecutive d per reg -> b64
      short* dst = (rr < 32) ? Qb : Kb;
      const float mul = (rr < 32) ? QSCALE : 1.0f;
      const int dbase = (rr & 31) + quad * 4;
      const size_t rowb = ((size_t)b * 8 + h) * 1024;
      for (int j = 0; j < 4; j++) {
        int n = n0 + wn + j * 16 + l15;
        short4_ sv;
        for (int r = 0; r < 4; r++) sv[r] = f2bf(acc[i][j][r] * mul);
        *(short4_*)(dst + (rowb + n) * 32 + dbase) = sv;
      }
    } else {  // v: [b,h,d,s]
      const int dv = (rr - 64) + quad * 4;
      const size_t base = (((size_t)b * 8 + h) * 32 + dv) * 1024;
      for (int j = 0; j < 4; j++) {
        int n = n0 + wn + j * 16 + l15;
        for (int r = 0; r < 4; r++) Vb[base + (size_t)r * 1024 + n] = f2bf(acc[i][j][r]);
      }
    }
  }
}

// ---------------------------------------------------------------------------
// Flash cross-attention. Block = 64 queries x (b,h); 4 waves; 256-key tiles
// staged cooperatively into LDS via global_load_lds (XOR-swizzled, no pad).
// S^T = MFMA(A=K, B=Q): lane holds P^T[sk=quad*4+r][sq=l15]; two S^T
// fragments concatenate into one 16x16x32 A operand under the k-slot map
// phi(q*8+o) = pr*32 + (o>>2)*16 + q*4 + (o&3); V-operand reads match phi.
// p = exp2(score), scale pre-folded into Q; no running max (scores bounded).
// ---------------------------------------------------------------------------
__global__ __launch_bounds__(256) void attn_kernel(const short* __restrict__ Qb,
                                                   const short* __restrict__ Kb,
                                                   const short* __restrict__ Vb,
                                                   short* __restrict__ AO) {
  const int qt = blockIdx.x, h = blockIdx.y, b = blockIdx.z;
  const int t = threadIdx.x;
  const int w = t >> 6, lane = t & 63, l15 = lane & 15, quad = lane >> 4;
  const size_t hb = (size_t)(b * 8 + h);
  const f32x4 z4 = {0.f, 0.f, 0.f, 0.f};
  __shared__ short Ks[256 * 32];  // [sk][d], 16B-chunk col ^ ((sk>>1)&3)
  __shared__ short Vs[32 * 256];  // [dv][sk_loc], 16B-chunk col ^ (dv&15)

  // Q fragment (B operand): [n=sq=l15][k=d=quad*8+j]
  const short8 bq = *(const short8*)(Qb + (hb * 1024 + qt * 64 + w * 16 + l15) * 32 + quad * 8);
  const short* Kg = Kb + hb * 1024 * 32;
  const short* Vg = Vb + hb * 32 * 1024;

  // staging lane roles
  const int rk_off = lane >> 2;  // K: 16 rows/wave-pass, 4 chunks/row
  const int ck = lane & 3;
  const int rv_off = lane >> 5;  // V: 2 rows/wave-pass, 32 chunks/row
  const int cv = lane & 31;
  // K fragment read base (shorts): row l15 (+j*16), swizzled chunk
  const int kread = l15 * 32 + ((quad ^ ((l15 >> 1) & 3)) * 8);

  f32x4 accO[2][2];
  accO[0][0] = z4; accO[0][1] = z4; accO[1][0] = z4; accO[1][1] = z4;
  float lsum = 0.f;

  for (int k0 = 0; k0 < 1024; k0 += 256) {
    __syncthreads();  // previous tile fully consumed
    for (int p = 0; p < 4; ++p) {
      const int rk = (w * 4 + p) * 16 + rk_off;
      load_lds16(Kg + (size_t)(k0 + rk) * 32 + ((ck ^ ((rk >> 1) & 3)) * 8),
                 &Ks[(w * 4 + p) * 512]);
      const int rv = (w * 4 + p) * 2 + rv_off;
      load_lds16(Vg + (size_t)rv * 1024 + k0 + ((cv ^ (rv & 15)) * 8),
                 &Vs[(w * 4 + p) * 512]);
    }
    __syncthreads();  // compiler drains vmcnt before the barrier

    for (int pr = 0; pr < 8; ++pr) {
      const short8 ak0 = *(const short8*)&Ks[(2 * pr) * 512 + kread];
      const short8 ak1 = *(const short8*)&Ks[(2 * pr + 1) * 512 + kread];
      f32x4 st0 = MFMA16(ak0, bq, z4);
      f32x4 st1 = MFMA16(ak1, bq, z4);
      union { short8 s; uint4_ u; } apv;
      float p0 = fast_exp2(st0[0]), p1 = fast_exp2(st0[1]);
      float p2 = fast_exp2(st0[2]), p3 = fast_exp2(st0[3]);
      float p4 = fast_exp2(st1[0]), p5 = fast_exp2(st1[1]);
      float p6 = fast_exp2(st1[2]), p7 = fast_exp2(st1[3]);
      lsum += ((p0 + p1) + (p2 + p3)) + ((p4 + p5) + (p6 + p7));
      apv.u[0] = pk2bf(p0, p1); apv.u[1] = pk2bf(p2, p3);
      apv.u[2] = pk2bf(p4, p5); apv.u[3] = pk2bf(p6, p7);
      // V operand: B[n=dv][k-slot] = V[dv][pr*32 + quad*4 + {0..3}] and +16
      const int cg = pr * 4 + (quad >> 1);
      const int so = (quad & 1) * 4;
      for (int dvt = 0; dvt < 2; ++dvt) {
        const int dvrow = (dvt * 16 + l15) * 256;
        union { short8 s; short4_ hh[2]; } bv;
        bv.hh[0] = *(const short4_*)&Vs[dvrow + ((cg ^ l15) * 8) + so];
        bv.hh[1] = *(const short4_*)&Vs[dvrow + (((cg + 2) ^ l15) * 8) + so];
        accO[dvt][pr & 1] = MFMA16(apv.s, bv.s, accO[dvt][pr & 1]);
      }
    }
  }

  // l(sq): sum lane-local partial over the 4 quads, broadcast to C-layout rows
  lsum += __shfl_xor(lsum, 16);
  lsum += __shfl_xor(lsum, 32);
  const int sqb = qt * 64 + w * 16;
  for (int r = 0; r < 4; r++) {
    float lr = __shfl(lsum, quad * 4 + r, 16);
    float inv = 1.0f / lr;
    int sq = sqb + quad * 4 + r;
    for (int dvt = 0; dvt < 2; dvt++) {
      float ov = accO[dvt][0][r] + accO[dvt][1][r];
      AO[((size_t)b * 256 + h * 32 + dvt * 16 + l15) * 1024 + sq] = f2bf(ov * inv);
    }
  }
}

// ---------------------------------------------------------------------------
// Output GEMM: out_f32[b,m,n] = sum_k W[m,k]*X_bf16[b,k,n] + bias[m] + resid
// ---------------------------------------------------------------------------
__global__ __launch_bounds__(256) void gemm_out_kernel(const float* __restrict__ W,
                                                       const short* __restrict__ X,
                                                       const float* __restrict__ bias,
                                                       const float* __restrict__ resid,
                                                       float* __restrict__ out) {
  const int m0 = blockIdx.x * 128;
  const int n0 = blockIdx.y * 128;
  const int b = blockIdx.z;
  const int t = threadIdx.x;
  __shared__ short As[128][32];
  __shared__ short Bs[128][32];
  const int w = t >> 6, lane = t & 63, l15 = lane & 15, quad = lane >> 4;
  const int wm = (w >> 1) * 64, wn = (w & 1) * 64;
  const f32x4 z4 = {0.f, 0.f, 0.f, 0.f};
  f32x4 acc[4][4];
  for (int i = 0; i < 4; i++)
    for (int j = 0; j < 4; j++) acc[i][j] = z4;
  const int mm = t >> 1, half = (t & 1) * 16;
  const float* wrow = W + (size_t)(m0 + mm) * 256 + half;
  const size_t xbase = (size_t)b * 256 * 1024 + n0;

  for (int k0 = 0; k0 < 256; k0 += 32) {
    __syncthreads();
    {
      const float* wp = wrow + k0;
      float4 a0 = *(const float4*)(wp);
      float4 a1 = *(const float4*)(wp + 4);
      float4 a2 = *(const float4*)(wp + 8);
      float4 a3 = *(const float4*)(wp + 12);
      short8 s0, s1;
      s0[0] = f2bf(a0.x); s0[1] = f2bf(a0.y); s0[2] = f2bf(a0.z); s0[3] = f2bf(a0.w);
      s0[4] = f2bf(a1.x); s0[5] = f2bf(a1.y); s0[6] = f2bf(a1.z); s0[7] = f2bf(a1.w);
      s1[0] = f2bf(a2.x); s1[1] = f2bf(a2.y); s1[2] = f2bf(a2.z); s1[3] = f2bf(a2.w);
      s1[4] = f2bf(a3.x); s1[5] = f2bf(a3.y); s1[6] = f2bf(a3.z); s1[7] = f2bf(a3.w);
      *(short8*)&As[mm][half] = s0;
      *(short8*)&As[mm][half + 8] = s1;
    }
    for (int p = 0; p < 4; ++p) {
      int kk = p * 8 + (t >> 5);
      int n4 = (t & 31) * 4;
      short4_ xv = *(const short4_*)(X + xbase + (size_t)(k0 + kk) * 1024 + n4);
      Bs[n4 + 0][kk] = xv[0];
      Bs[n4 + 1][kk] = xv[1];
      Bs[n4 + 2][kk] = xv[2];
      Bs[n4 + 3][kk] = xv[3];
    }
    __syncthreads();
    short8 af[4], bfr[4];
    for (int i = 0; i < 4; i++) af[i] = *(const short8*)&As[wm + i * 16 + l15][quad * 8];
    for (int j = 0; j < 4; j++) bfr[j] = *(const short8*)&Bs[wn + j * 16 + l15][quad * 8];
    for (int i = 0; i < 4; i++)
      for (int j = 0; j < 4; j++) acc[i][j] = MFMA16(af[i], bfr[j], acc[i][j]);
  }
  for (int i = 0; i < 4; i++)
    for (int j = 0; j < 4; j++) {
      int m = m0 + wm + i * 16 + quad * 4;
      int n = n0 + wn + j * 16 + l15;
      size_t off = ((size_t)b * 256 + m) * 1024 + n;
      for (int r = 0; r < 4; r++)
        out[off + (size_t)r * 1024] = acc[i][j][r] + bias[m + r] + resid[off + (size_t)r * 1024];
    }
}

// ---------------------------------------------------------------------------
extern "C" void kernel_launch(void* const* d_in, const int* in_sizes, int n_in,
                              void* d_out, int out_size, void* d_ws, size_t ws_size,
                              hipStream_t stream) {
  const float* xA = (const float*)d_in[0];
  const float* xB = (const float*)d_in[1];
  const float* gA = (const float*)d_in[2];
  const float* bA = (const float*)d_in[3];
  const float* gB = (const float*)d_in[4];
  const float* bB = (const float*)d_in[5];
  const float* WqkvA = (const float*)d_in[6];
  const float* WqkvB = (const float*)d_in[7];
  const float* WoutA = (const float*)d_in[8];
  const float* boutA = (const float*)d_in[9];
  const float* WoutB = (const float*)d_in[10];
  const float* boutB = (const float*)d_in[11];
  float* out = (float*)d_out;
  char* ws = (char*)d_ws;
  // workspace layout (96 MB total)
  float* nA  = (float*)(ws);                  // 16 MB fp32 norm A
  float* nB  = (float*)(ws + 16777216);       // 16 MB fp32 norm B
  short* QbA = (short*)(ws + 33554432);       // 8 MB bf16 Q_A [b,h,s,d] (pre-scaled)
  short* KbA = (short*)(ws + 41943040);       // 8 MB bf16 K_A [b,h,s,d]
  short* VbA = (short*)(ws + 50331648);       // 8 MB bf16 V_A [b,h,d,s]
  short* QbB = (short*)(ws + 58720256);
  short* KbB = (short*)(ws + 67108864);
  short* VbB = (short*)(ws + 75497472);
  short* aoA = (short*)(ws + 83886080);       // 8 MB bf16 attn-out A [b,c,s]
  short* aoB = (short*)(ws + 92274688);       // 8 MB bf16 attn-out B

  gn_kernel<<<256, 256, 0, stream>>>(xA, gA, bA, nA);
  gn_kernel<<<256, 256, 0, stream>>>(xB, gB, bB, nB);
  gemm_qkv_kernel<<<dim3(6, 8, 16), 256, 0, stream>>>(WqkvA, nA, QbA, KbA, VbA);
  gemm_qkv_kernel<<<dim3(6, 8, 16), 256, 0, stream>>>(WqkvB, nB, QbB, KbB, VbB);
  // branch A output: attn(qB -> kA,vA); branch B: attn(qA -> kB,vB)
  attn_kernel<<<dim3(16, 8, 16), 256, 0, stream>>>(QbB, KbA, VbA, aoA);
  attn_kernel<<<dim3(16, 8, 16), 256, 0, stream>>>(QbA, KbB, VbB, aoB);
  gemm_out_kernel<<<dim3(2, 8, 16), 256, 0, stream>>>(WoutA, aoA, boutA, nA, out);
  gemm_out_kernel<<<dim3(2, 8, 16), 256, 0, stream>>>(WoutB, aoB, boutB, nB, out + 4194304);
}

// Round 5
// 237.538 us; speedup vs baseline: 2.3396x; 1.4642x over previous
//
#include <hip/hip_runtime.h>
#include <hip/hip_bf16.h>
#include <math.h>

typedef __attribute__((ext_vector_type(8))) short short8;
typedef __attribute__((ext_vector_type(4))) short short4_;
typedef __attribute__((ext_vector_type(4))) float f32x4;
typedef __attribute__((ext_vector_type(4))) unsigned int uint4_;

#define MFMA16(a, b, c) __builtin_amdgcn_mfma_f32_16x16x32_bf16((a), (b), (c), 0, 0, 0)

// fp32 -> bf16 round-to-nearest-even
__device__ __forceinline__ short f2bf(float f) {
  union { float f; unsigned u; } v; v.f = f;
  unsigned r = v.u + 0x7fffu + ((v.u >> 16) & 1u);
  return (short)(r >> 16);
}

__device__ __forceinline__ float bf2f(short s) {
  union { float f; unsigned u; } v; v.u = ((unsigned)(unsigned short)s) << 16;
  return v.f;
}

// pack two fp32 -> 2x bf16 in one dword
__device__ __forceinline__ unsigned pk2bf(float a, float b) {
  union { __hip_bfloat162 h2; unsigned u; } cv;
  cv.h2 = __float22bfloat162_rn(float2{a, b});
  return cv.u;
}

__device__ __forceinline__ float fast_exp2(float x) {
#if __has_builtin(__builtin_amdgcn_exp2f)
  return __builtin_amdgcn_exp2f(x);
#else
  return __exp2f(x);
#endif
}

// async global -> LDS, 16 B per lane; LDS dest = base + lane*16 (base wave-uniform)
__device__ __forceinline__ void load_lds16(const void* g, void* l) {
  __builtin_amdgcn_global_load_lds((const __attribute__((address_space(1))) void*)g,
                                   (__attribute__((address_space(3))) void*)l, 16, 0, 0);
}

// scale(1/sqrt(256)) * log2(e), folded into Q values at the QKV GEMM epilogue
#define QSCALE 0.09016844005556f

// ---------------------------------------------------------------------------
// Weight convert: WqkvA(96 blk), WqkvB(96), WoutA(32), WoutB(32) fp32->bf16.
// ---------------------------------------------------------------------------
__global__ __launch_bounds__(256) void wcvt_kernel(const float* __restrict__ wqA,
                                                   const float* __restrict__ wqB,
                                                   const float* __restrict__ woA,
                                                   const float* __restrict__ woB,
                                                   short* __restrict__ oqA,
                                                   short* __restrict__ oqB,
                                                   short* __restrict__ ooA,
                                                   short* __restrict__ ooB) {
  int blk = blockIdx.x;
  const float* src; short* dst; int base;
  if (blk < 96) { src = wqA; dst = oqA; base = blk; }
  else if (blk < 192) { src = wqB; dst = oqB; base = blk - 96; }
  else if (blk < 224) { src = woA; dst = ooA; base = blk - 192; }
  else { src = woB; dst = ooB; base = blk - 224; }
  int idx = base * 2048 + threadIdx.x * 8;
  float4 a = *(const float4*)(src + idx);
  float4 b = *(const float4*)(src + idx + 4);
  short8 o;
  o[0] = f2bf(a.x); o[1] = f2bf(a.y); o[2] = f2bf(a.z); o[3] = f2bf(a.w);
  o[4] = f2bf(b.x); o[5] = f2bf(b.y); o[6] = f2bf(b.z); o[7] = f2bf(b.w);
  *(short8*)(dst + idx) = o;
}

// ---------------------------------------------------------------------------
// GroupNorm: block = (b, g); 16 ch x 1024 s. Thread t holds the full
// 16-channel column for s=4t..4t+3 -> in-register transpose, write bf16
// Xt[b, s, c] (rows of 256 ch; this block covers 16 ch = 32 B per row).
// ---------------------------------------------------------------------------
__global__ __launch_bounds__(256) void gn_kernel(const float* __restrict__ x,
                                                 const float* __restrict__ gamma,
                                                 const float* __restrict__ beta,
                                                 short* __restrict__ Xt) {
  const int blk = blockIdx.x;  // b*16 + g
  const int b = blk >> 4, g = blk & 15;
  const int t = threadIdx.x;
  const size_t base = (size_t)blk * 16384;
  const float4* xp = (const float4*)(x + base);
  float s = 0.f, q = 0.f;
  float4 vals[16];
  for (int i = 0; i < 16; ++i) {
    float4 v = xp[t + i * 256];  // channel g*16+i, s = 4t..4t+3
    vals[i] = v;
    s += v.x + v.y + v.z + v.w;
    q += v.x * v.x + v.y * v.y + v.z * v.z + v.w * v.w;
  }
  __shared__ float rs[256], rq[256];
  rs[t] = s; rq[t] = q;
  __syncthreads();
  for (int o = 128; o > 0; o >>= 1) {
    if (t < o) { rs[t] += rs[t + o]; rq[t] += rq[t + o]; }
    __syncthreads();
  }
  __shared__ float sh_mu, sh_inv;
  if (t == 0) {
    float mu = rs[0] * (1.f / 16384.f);
    float var = rq[0] * (1.f / 16384.f) - mu * mu;
    sh_mu = mu;
    sh_inv = rsqrtf(var + 1e-5f);
  }
  __syncthreads();
  const float mu = sh_mu, inv = sh_inv;
  short tmp[4][16];
#pragma unroll
  for (int i = 0; i < 16; ++i) {
    int c = (g << 4) + i;
    float ga = gamma[c] * inv;
    float be = beta[c] - mu * ga;
    float4 v = vals[i];
    tmp[0][i] = f2bf(v.x * ga + be);
    tmp[1][i] = f2bf(v.y * ga + be);
    tmp[2][i] = f2bf(v.z * ga + be);
    tmp[3][i] = f2bf(v.w * ga + be);
  }
  short* orow = Xt + ((size_t)b * 1024 + 4 * t) * 256 + (g << 4);
#pragma unroll
  for (int j = 0; j < 4; ++j) {
    *(short8*)(orow + j * 256) = *(const short8*)&tmp[j][0];
    *(short8*)(orow + j * 256 + 8) = *(const short8*)&tmp[j][8];
  }
}

// ---------------------------------------------------------------------------
// QKV GEMM: Y[b,m,n] = sum_k Wb_bf16[m,k] * Xt_bf16[b,n,k]; M=768,K=256,N=1024.
// 128x128 tile, 4 waves of 64x64, BK=64. Both tiles staged via global_load_lds
// (16 B/lane) with XOR chunk-swizzle (chunk ^ (row&7)) -> conflict-free reads.
// Epilogue: Q->[b,h,s,d]*QSCALE, K->[b,h,s,d], V->[b,h,d,s].
// ---------------------------------------------------------------------------
__global__ __launch_bounds__(256) void gemm_qkv_kernel(const short* __restrict__ Wb,
                                                       const short* __restrict__ Xt,
                                                       short* __restrict__ Qb,
                                                       short* __restrict__ Kb,
                                                       short* __restrict__ Vb) {
  const int m0 = blockIdx.x * 128, n0 = blockIdx.y * 128, b = blockIdx.z;
  const int t = threadIdx.x;
  __shared__ short As[128 * 64];
  __shared__ short Bs[128 * 64];
  const int w = t >> 6, lane = t & 63, l15 = lane & 15, quad = lane >> 4;
  const int wm = (w >> 1) * 64, wn = (w & 1) * 64;
  const f32x4 z4 = {0.f, 0.f, 0.f, 0.f};
  f32x4 acc[4][4];
  for (int i = 0; i < 4; i++)
    for (int j = 0; j < 4; j++) acc[i][j] = z4;

  const int srow = lane >> 3, cpos = lane & 7;
  const int swz = (cpos ^ srow) * 8;
  const short* wg = Wb + (size_t)(m0 + w * 32 + srow) * 256 + swz;
  const short* xg = Xt + ((size_t)b * 1024 + n0 + w * 32 + srow) * 256 + swz;
  short* lA = &As[(w * 32) * 64];
  short* lB = &Bs[(w * 32) * 64];

  for (int k0 = 0; k0 < 256; k0 += 64) {
    __syncthreads();
#pragma unroll
    for (int qq = 0; qq < 4; ++qq) {
      load_lds16(wg + (size_t)qq * 8 * 256 + k0, lA + qq * 8 * 64);
      load_lds16(xg + (size_t)qq * 8 * 256 + k0, lB + qq * 8 * 64);
    }
    __syncthreads();
#pragma unroll
    for (int s = 0; s < 2; ++s) {
      const int cc = ((s * 4 + quad) ^ (l15 & 7)) * 8;
      short8 af[4], bfb[4];
      for (int i = 0; i < 4; i++) af[i] = *(const short8*)&As[(wm + i * 16 + l15) * 64 + cc];
      for (int j = 0; j < 4; j++) bfb[j] = *(const short8*)&Bs[(wn + j * 16 + l15) * 64 + cc];
      for (int i = 0; i < 4; i++)
        for (int j = 0; j < 4; j++) acc[i][j] = MFMA16(af[i], bfb[j], acc[i][j]);
    }
  }
  // Epilogue: 16-aligned channel blocks never cross q/k/v or head boundaries.
  for (int i = 0; i < 4; i++) {
    int mi = m0 + wm + i * 16;
    int h = mi / 96;
    int rr = mi - h * 96;
    if (rr < 64) {  // q or k: [b,h,s,d]
      short* dst = (rr < 32) ? Qb : Kb;
      const float mul = (rr < 32) ? QSCALE : 1.0f;
      const int dbase = (rr & 31) + quad * 4;
      const size_t rowb = ((size_t)b * 8 + h) * 1024;
      for (int j = 0; j < 4; j++) {
        int n = n0 + wn + j * 16 + l15;
        short4_ sv;
        for (int r = 0; r < 4; r++) sv[r] = f2bf(acc[i][j][r] * mul);
        *(short4_*)(dst + (rowb + n) * 32 + dbase) = sv;
      }
    } else {  // v: [b,h,d,s]
      const int dv = (rr - 64) + quad * 4;
      const size_t vb = (((size_t)b * 8 + h) * 32 + dv) * 1024;
      for (int j = 0; j < 4; j++) {
        int n = n0 + wn + j * 16 + l15;
        for (int r = 0; r < 4; r++) Vb[vb + (size_t)r * 1024 + n] = f2bf(acc[i][j][r]);
      }
    }
  }
}

// ---------------------------------------------------------------------------
// Flash cross-attention (unchanged core from R4; AO now written [b,s,c]).
// ---------------------------------------------------------------------------
__global__ __launch_bounds__(256) void attn_kernel(const short* __restrict__ Qb,
                                                   const short* __restrict__ Kb,
                                                   const short* __restrict__ Vb,
                                                   short* __restrict__ AO) {
  const int qt = blockIdx.x, h = blockIdx.y, b = blockIdx.z;
  const int t = threadIdx.x;
  const int w = t >> 6, lane = t & 63, l15 = lane & 15, quad = lane >> 4;
  const size_t hb = (size_t)(b * 8 + h);
  const f32x4 z4 = {0.f, 0.f, 0.f, 0.f};
  __shared__ short Ks[256 * 32];  // [sk][d], 16B-chunk col ^ ((sk>>1)&3)
  __shared__ short Vs[32 * 256];  // [dv][sk_loc], 16B-chunk col ^ (dv&15)

  const short8 bq = *(const short8*)(Qb + (hb * 1024 + qt * 64 + w * 16 + l15) * 32 + quad * 8);
  const short* Kg = Kb + hb * 1024 * 32;
  const short* Vg = Vb + hb * 32 * 1024;

  const int rk_off = lane >> 2;
  const int ck = lane & 3;
  const int rv_off = lane >> 5;
  const int cv = lane & 31;
  const int kread = l15 * 32 + ((quad ^ ((l15 >> 1) & 3)) * 8);

  f32x4 accO[2][2];
  accO[0][0] = z4; accO[0][1] = z4; accO[1][0] = z4; accO[1][1] = z4;
  float lsum = 0.f;

  for (int k0 = 0; k0 < 1024; k0 += 256) {
    __syncthreads();
    for (int p = 0; p < 4; ++p) {
      const int rk = (w * 4 + p) * 16 + rk_off;
      load_lds16(Kg + (size_t)(k0 + rk) * 32 + ((ck ^ ((rk >> 1) & 3)) * 8),
                 &Ks[(w * 4 + p) * 512]);
      const int rv = (w * 4 + p) * 2 + rv_off;
      load_lds16(Vg + (size_t)rv * 1024 + k0 + ((cv ^ (rv & 15)) * 8),
                 &Vs[(w * 4 + p) * 512]);
    }
    __syncthreads();

    for (int pr = 0; pr < 8; ++pr) {
      const short8 ak0 = *(const short8*)&Ks[(2 * pr) * 512 + kread];
      const short8 ak1 = *(const short8*)&Ks[(2 * pr + 1) * 512 + kread];
      f32x4 st0 = MFMA16(ak0, bq, z4);
      f32x4 st1 = MFMA16(ak1, bq, z4);
      union { short8 s; uint4_ u; } apv;
      float p0 = fast_exp2(st0[0]), p1 = fast_exp2(st0[1]);
      float p2 = fast_exp2(st0[2]), p3 = fast_exp2(st0[3]);
      float p4 = fast_exp2(st1[0]), p5 = fast_exp2(st1[1]);
      float p6 = fast_exp2(st1[2]), p7 = fast_exp2(st1[3]);
      lsum += ((p0 + p1) + (p2 + p3)) + ((p4 + p5) + (p6 + p7));
      apv.u[0] = pk2bf(p0, p1); apv.u[1] = pk2bf(p2, p3);
      apv.u[2] = pk2bf(p4, p5); apv.u[3] = pk2bf(p6, p7);
      const int cg = pr * 4 + (quad >> 1);
      const int so = (quad & 1) * 4;
      for (int dvt = 0; dvt < 2; ++dvt) {
        const int dvrow = (dvt * 16 + l15) * 256;
        union { short8 s; short4_ hh[2]; } bv;
        bv.hh[0] = *(const short4_*)&Vs[dvrow + ((cg ^ l15) * 8) + so];
        bv.hh[1] = *(const short4_*)&Vs[dvrow + (((cg + 2) ^ l15) * 8) + so];
        accO[dvt][pr & 1] = MFMA16(apv.s, bv.s, accO[dvt][pr & 1]);
      }
    }
  }

  lsum += __shfl_xor(lsum, 16);
  lsum += __shfl_xor(lsum, 32);
  const int sqb = qt * 64 + w * 16;
  for (int r = 0; r < 4; r++) {
    float lr = __shfl(lsum, quad * 4 + r, 16);
    float inv = 1.0f / lr;
    int sq = sqb + quad * 4 + r;
    short* orow = AO + ((size_t)b * 1024 + sq) * 256 + h * 32 + l15;
    orow[0] = f2bf((accO[0][0][r] + accO[0][1][r]) * inv);
    orow[16] = f2bf((accO[1][0][r] + accO[1][1][r]) * inv);
  }
}

// ---------------------------------------------------------------------------
// Output GEMM: out[b,m,n] = sum_k Wob[m,k]*ao[b,n,k] + bias[m] + norm[b,m,n]
// M=256,K=256,N=1024. Same staging as qkv. Residual staged from Xt[b,s,c]
// into (reused) LDS with 16-chunk swizzle, read back as conflict-free b64.
// ---------------------------------------------------------------------------
__global__ __launch_bounds__(256) void gemm_out_kernel(const short* __restrict__ Wob,
                                                       const short* __restrict__ ao,
                                                       const float* __restrict__ bias,
                                                       const short* __restrict__ Xt,
                                                       float* __restrict__ out) {
  const int m0 = blockIdx.x * 128, n0 = blockIdx.y * 128, b = blockIdx.z;
  const int t = threadIdx.x;
  __shared__ short smem[128 * 64 * 2];
  short* As = smem;
  short* Bs = smem + 128 * 64;
  const int w = t >> 6, lane = t & 63, l15 = lane & 15, quad = lane >> 4;
  const int wm = (w >> 1) * 64, wn = (w & 1) * 64;
  const f32x4 z4 = {0.f, 0.f, 0.f, 0.f};
  f32x4 acc[4][4];
  for (int i = 0; i < 4; i++)
    for (int j = 0; j < 4; j++) acc[i][j] = z4;

  const int srow = lane >> 3, cpos = lane & 7;
  const int swz = (cpos ^ srow) * 8;
  const short* wg = Wob + (size_t)(m0 + w * 32 + srow) * 256 + swz;
  const short* xg = ao + ((size_t)b * 1024 + n0 + w * 32 + srow) * 256 + swz;
  short* lA = &As[(w * 32) * 64];
  short* lB = &Bs[(w * 32) * 64];

  for (int k0 = 0; k0 < 256; k0 += 64) {
    __syncthreads();
#pragma unroll
    for (int qq = 0; qq < 4; ++qq) {
      load_lds16(wg + (size_t)qq * 8 * 256 + k0, lA + qq * 8 * 64);
      load_lds16(xg + (size_t)qq * 8 * 256 + k0, lB + qq * 8 * 64);
    }
    __syncthreads();
#pragma unroll
    for (int s = 0; s < 2; ++s) {
      const int cc = ((s * 4 + quad) ^ (l15 & 7)) * 8;
      short8 af[4], bfb[4];
      for (int i = 0; i < 4; i++) af[i] = *(const short8*)&As[(wm + i * 16 + l15) * 64 + cc];
      for (int j = 0; j < 4; j++) bfb[j] = *(const short8*)&Bs[(wn + j * 16 + l15) * 64 + cc];
      for (int i = 0; i < 4; i++)
        for (int j = 0; j < 4; j++) acc[i][j] = MFMA16(af[i], bfb[j], acc[i][j]);
    }
  }

  // Stage residual tile: rows n (128) x 128 c (this block's m-range), from
  // Xt[b, n, m0+...]. 16 chunks/row, swizzle chunk ^ (row&15).
  __syncthreads();
  {
    const int rrow = lane >> 4, rc = lane & 15;
    for (int qq = 0; qq < 8; ++qq) {
      int row = w * 32 + qq * 4 + rrow;
      load_lds16(Xt + ((size_t)b * 1024 + n0 + row) * 256 + m0 + ((rc ^ (row & 15)) * 8),
                 &smem[(w * 32 + qq * 4) * 128]);
    }
  }
  __syncthreads();

  for (int i = 0; i < 4; i++)
    for (int j = 0; j < 4; j++) {
      int m = m0 + wm + i * 16 + quad * 4;
      int nl = wn + j * 16 + l15;
      int n = n0 + nl;
      size_t off = ((size_t)b * 256 + m) * 1024 + n;
      const int chunk = (wm >> 3) + i * 2 + (quad >> 1);
      short4_ rv = *(const short4_*)&smem[nl * 128 + ((chunk ^ (nl & 15)) * 8) + (quad & 1) * 4];
      for (int r = 0; r < 4; r++)
        out[off + (size_t)r * 1024] = acc[i][j][r] + bias[m + r] + bf2f(rv[r]);
    }
}

// ---------------------------------------------------------------------------
extern "C" void kernel_launch(void* const* d_in, const int* in_sizes, int n_in,
                              void* d_out, int out_size, void* d_ws, size_t ws_size,
                              hipStream_t stream) {
  const float* xA = (const float*)d_in[0];
  const float* xB = (const float*)d_in[1];
  const float* gA = (const float*)d_in[2];
  const float* bA = (const float*)d_in[3];
  const float* gB = (const float*)d_in[4];
  const float* bB = (const float*)d_in[5];
  const float* WqkvA = (const float*)d_in[6];
  const float* WqkvB = (const float*)d_in[7];
  const float* WoutA = (const float*)d_in[8];
  const float* boutA = (const float*)d_in[9];
  const float* WoutB = (const float*)d_in[10];
  const float* boutB = (const float*)d_in[11];
  float* out = (float*)d_out;
  char* ws = (char*)d_ws;
  // workspace layout (~81 MB)
  short* XtA = (short*)(ws);                   // 8 MB bf16 norm A [b,s,c]
  short* XtB = (short*)(ws + 8388608);         // 8 MB bf16 norm B [b,s,c]
  short* QbA = (short*)(ws + 16777216);        // 8 MB [b,h,s,d] (pre-scaled)
  short* KbA = (short*)(ws + 25165824);
  short* VbA = (short*)(ws + 33554432);        // [b,h,d,s]
  short* QbB = (short*)(ws + 41943040);
  short* KbB = (short*)(ws + 50331648);
  short* VbB = (short*)(ws + 58720256);
  short* aoA = (short*)(ws + 67108864);        // 8 MB attn-out A [b,s,c]
  short* aoB = (short*)(ws + 75497472);
  short* WqbA = (short*)(ws + 83886080);       // 384 KB
  short* WqbB = (short*)(ws + 84279296);
  short* WobA = (short*)(ws + 84672512);       // 128 KB
  short* WobB = (short*)(ws + 84803584);

  wcvt_kernel<<<256, 256, 0, stream>>>(WqkvA, WqkvB, WoutA, WoutB, WqbA, WqbB, WobA, WobB);
  gn_kernel<<<256, 256, 0, stream>>>(xA, gA, bA, XtA);
  gn_kernel<<<256, 256, 0, stream>>>(xB, gB, bB, XtB);
  gemm_qkv_kernel<<<dim3(6, 8, 16), 256, 0, stream>>>(WqbA, XtA, QbA, KbA, VbA);
  gemm_qkv_kernel<<<dim3(6, 8, 16), 256, 0, stream>>>(WqbB, XtB, QbB, KbB, VbB);
  // branch A output: attn(qB -> kA,vA); branch B: attn(qA -> kB,vB)
  attn_kernel<<<dim3(16, 8, 16), 256, 0, stream>>>(QbB, KbA, VbA, aoA);
  attn_kernel<<<dim3(16, 8, 16), 256, 0, stream>>>(QbA, KbB, VbB, aoB);
  gemm_out_kernel<<<dim3(2, 8, 16), 256, 0, stream>>>(WobA, aoA, boutA, XtA, out);
  gemm_out_kernel<<<dim3(2, 8, 16), 256, 0, stream>>>(WobB, aoB, boutB, XtB, out + 4194304);
}

// Round 6
// 226.621 us; speedup vs baseline: 2.4523x; 1.0482x over previous
//
#include <hip/hip_runtime.h>
#include <hip/hip_bf16.h>
#include <math.h>

typedef __attribute__((ext_vector_type(8))) short short8;
typedef __attribute__((ext_vector_type(4))) short short4_;
typedef __attribute__((ext_vector_type(4))) float f32x4;
typedef __attribute__((ext_vector_type(4))) unsigned int uint4_;

#define MFMA16(a, b, c) __builtin_amdgcn_mfma_f32_16x16x32_bf16((a), (b), (c), 0, 0, 0)

// fp32 -> bf16 round-to-nearest-even
__device__ __forceinline__ short f2bf(float f) {
  union { float f; unsigned u; } v; v.f = f;
  unsigned r = v.u + 0x7fffu + ((v.u >> 16) & 1u);
  return (short)(r >> 16);
}

__device__ __forceinline__ float bf2f(short s) {
  union { float f; unsigned u; } v; v.u = ((unsigned)(unsigned short)s) << 16;
  return v.f;
}

// pack two fp32 -> 2x bf16 (TRUNCATED) in one dword: a -> low, b -> high.
// v_perm_b32 grabs the high 16 bits of each float in a single instruction.
__device__ __forceinline__ unsigned pktrunc(float a, float b) {
#if __has_builtin(__builtin_amdgcn_perm)
  return __builtin_amdgcn_perm(__builtin_bit_cast(unsigned, b),
                               __builtin_bit_cast(unsigned, a), 0x07060302u);
#else
  return (__builtin_bit_cast(unsigned, b) & 0xffff0000u) |
         (__builtin_bit_cast(unsigned, a) >> 16);
#endif
}

__device__ __forceinline__ float fast_exp2(float x) {
#if __has_builtin(__builtin_amdgcn_exp2f)
  return __builtin_amdgcn_exp2f(x);
#else
  return __exp2f(x);
#endif
}

// async global -> LDS, 16 B per lane; LDS dest = base + lane*16 (base wave-uniform)
__device__ __forceinline__ void load_lds16(const void* g, void* l) {
  __builtin_amdgcn_global_load_lds((const __attribute__((address_space(1))) void*)g,
                                   (__attribute__((address_space(3))) void*)l, 16, 0, 0);
}

// scale(1/sqrt(256)) * log2(e), folded into Q values at the QKV GEMM epilogue
#define QSCALE 0.09016844005556f

// ---------------------------------------------------------------------------
// Weight convert: WqkvA(96 blk), WqkvB(96), WoutA(32), WoutB(32) fp32->bf16.
// ---------------------------------------------------------------------------
__global__ __launch_bounds__(256) void wcvt_kernel(const float* __restrict__ wqA,
                                                   const float* __restrict__ wqB,
                                                   const float* __restrict__ woA,
                                                   const float* __restrict__ woB,
                                                   short* __restrict__ oqA,
                                                   short* __restrict__ oqB,
                                                   short* __restrict__ ooA,
                                                   short* __restrict__ ooB) {
  int blk = blockIdx.x;
  const float* src; short* dst; int base;
  if (blk < 96) { src = wqA; dst = oqA; base = blk; }
  else if (blk < 192) { src = wqB; dst = oqB; base = blk - 96; }
  else if (blk < 224) { src = woA; dst = ooA; base = blk - 192; }
  else { src = woB; dst = ooB; base = blk - 224; }
  int idx = base * 2048 + threadIdx.x * 8;
  float4 a = *(const float4*)(src + idx);
  float4 b = *(const float4*)(src + idx + 4);
  short8 o;
  o[0] = f2bf(a.x); o[1] = f2bf(a.y); o[2] = f2bf(a.z); o[3] = f2bf(a.w);
  o[4] = f2bf(b.x); o[5] = f2bf(b.y); o[6] = f2bf(b.z); o[7] = f2bf(b.w);
  *(short8*)(dst + idx) = o;
}

// ---------------------------------------------------------------------------
// GroupNorm: block = (b, g); 16 ch x 1024 s. Thread t holds the full
// 16-channel column for s=4t..4t+3 -> in-register transpose, write bf16
// Xt[b, s, c].
// ---------------------------------------------------------------------------
__global__ __launch_bounds__(256) void gn_kernel(const float* __restrict__ x,
                                                 const float* __restrict__ gamma,
                                                 const float* __restrict__ beta,
                                                 short* __restrict__ Xt) {
  const int blk = blockIdx.x;  // b*16 + g
  const int b = blk >> 4, g = blk & 15;
  const int t = threadIdx.x;
  const size_t base = (size_t)blk * 16384;
  const float4* xp = (const float4*)(x + base);
  float s = 0.f, q = 0.f;
  float4 vals[16];
  for (int i = 0; i < 16; ++i) {
    float4 v = xp[t + i * 256];  // channel g*16+i, s = 4t..4t+3
    vals[i] = v;
    s += v.x + v.y + v.z + v.w;
    q += v.x * v.x + v.y * v.y + v.z * v.z + v.w * v.w;
  }
  __shared__ float rs[256], rq[256];
  rs[t] = s; rq[t] = q;
  __syncthreads();
  for (int o = 128; o > 0; o >>= 1) {
    if (t < o) { rs[t] += rs[t + o]; rq[t] += rq[t + o]; }
    __syncthreads();
  }
  __shared__ float sh_mu, sh_inv;
  if (t == 0) {
    float mu = rs[0] * (1.f / 16384.f);
    float var = rq[0] * (1.f / 16384.f) - mu * mu;
    sh_mu = mu;
    sh_inv = rsqrtf(var + 1e-5f);
  }
  __syncthreads();
  const float mu = sh_mu, inv = sh_inv;
  short tmp[4][16];
#pragma unroll
  for (int i = 0; i < 16; ++i) {
    int c = (g << 4) + i;
    float ga = gamma[c] * inv;
    float be = beta[c] - mu * ga;
    float4 v = vals[i];
    tmp[0][i] = f2bf(v.x * ga + be);
    tmp[1][i] = f2bf(v.y * ga + be);
    tmp[2][i] = f2bf(v.z * ga + be);
    tmp[3][i] = f2bf(v.w * ga + be);
  }
  short* orow = Xt + ((size_t)b * 1024 + 4 * t) * 256 + (g << 4);
#pragma unroll
  for (int j = 0; j < 4; ++j) {
    *(short8*)(orow + j * 256) = *(const short8*)&tmp[j][0];
    *(short8*)(orow + j * 256 + 8) = *(const short8*)&tmp[j][8];
  }
}

// ---------------------------------------------------------------------------
// QKV GEMM: Y[b,m,n] = sum_k Wb_bf16[m,k] * Xt_bf16[b,n,k]; M=768,K=256,N=1024.
// 128x128 tile, 4 waves of 64x64, BK=64, global_load_lds staging.
// Epilogue: Q->[b,h,s,d]*QSCALE, K->[b,h,s,d], V->[b,h,d,s].
// ---------------------------------------------------------------------------
__global__ __launch_bounds__(256) void gemm_qkv_kernel(const short* __restrict__ Wb,
                                                       const short* __restrict__ Xt,
                                                       short* __restrict__ Qb,
                                                       short* __restrict__ Kb,
                                                       short* __restrict__ Vb) {
  const int m0 = blockIdx.x * 128, n0 = blockIdx.y * 128, b = blockIdx.z;
  const int t = threadIdx.x;
  __shared__ short As[128 * 64];
  __shared__ short Bs[128 * 64];
  const int w = t >> 6, lane = t & 63, l15 = lane & 15, quad = lane >> 4;
  const int wm = (w >> 1) * 64, wn = (w & 1) * 64;
  const f32x4 z4 = {0.f, 0.f, 0.f, 0.f};
  f32x4 acc[4][4];
  for (int i = 0; i < 4; i++)
    for (int j = 0; j < 4; j++) acc[i][j] = z4;

  const int srow = lane >> 3, cpos = lane & 7;
  const int swz = (cpos ^ srow) * 8;
  const short* wg = Wb + (size_t)(m0 + w * 32 + srow) * 256 + swz;
  const short* xg = Xt + ((size_t)b * 1024 + n0 + w * 32 + srow) * 256 + swz;
  short* lA = &As[(w * 32) * 64];
  short* lB = &Bs[(w * 32) * 64];

  for (int k0 = 0; k0 < 256; k0 += 64) {
    __syncthreads();
#pragma unroll
    for (int qq = 0; qq < 4; ++qq) {
      load_lds16(wg + (size_t)qq * 8 * 256 + k0, lA + qq * 8 * 64);
      load_lds16(xg + (size_t)qq * 8 * 256 + k0, lB + qq * 8 * 64);
    }
    __syncthreads();
#pragma unroll
    for (int s = 0; s < 2; ++s) {
      const int cc = ((s * 4 + quad) ^ (l15 & 7)) * 8;
      short8 af[4], bfb[4];
      for (int i = 0; i < 4; i++) af[i] = *(const short8*)&As[(wm + i * 16 + l15) * 64 + cc];
      for (int j = 0; j < 4; j++) bfb[j] = *(const short8*)&Bs[(wn + j * 16 + l15) * 64 + cc];
      for (int i = 0; i < 4; i++)
        for (int j = 0; j < 4; j++) acc[i][j] = MFMA16(af[i], bfb[j], acc[i][j]);
    }
  }
  for (int i = 0; i < 4; i++) {
    int mi = m0 + wm + i * 16;
    int h = mi / 96;
    int rr = mi - h * 96;
    if (rr < 64) {  // q or k: [b,h,s,d]
      short* dst = (rr < 32) ? Qb : Kb;
      const float mul = (rr < 32) ? QSCALE : 1.0f;
      const int dbase = (rr & 31) + quad * 4;
      const size_t rowb = ((size_t)b * 8 + h) * 1024;
      for (int j = 0; j < 4; j++) {
        int n = n0 + wn + j * 16 + l15;
        short4_ sv;
        for (int r = 0; r < 4; r++) sv[r] = f2bf(acc[i][j][r] * mul);
        *(short4_*)(dst + (rowb + n) * 32 + dbase) = sv;
      }
    } else {  // v: [b,h,d,s]
      const int dv = (rr - 64) + quad * 4;
      const size_t vb = (((size_t)b * 8 + h) * 32 + dv) * 1024;
      for (int j = 0; j < 4; j++) {
        int n = n0 + wn + j * 16 + l15;
        for (int r = 0; r < 4; r++) Vb[vb + (size_t)r * 1024 + n] = f2bf(acc[i][j][r]);
      }
    }
  }
}

// ---------------------------------------------------------------------------
// Flash cross-attention. Block = 128 queries x (b,h); 4 waves; each wave owns
// TWO 16-query blocks (K/V LDS reads amortized 2x). 256-key tiles staged via
// global_load_lds (XOR-swizzled). S^T = MFMA(A=K, B=Qs); P packed to bf16 by
// TRUNCATION (v_perm); l accumulated via ones-MFMA (C-layout matches rows).
// ---------------------------------------------------------------------------
__global__ __launch_bounds__(256) void attn_kernel(const short* __restrict__ Qb,
                                                   const short* __restrict__ Kb,
                                                   const short* __restrict__ Vb,
                                                   short* __restrict__ AO) {
  const int qt = blockIdx.x, h = blockIdx.y, b = blockIdx.z;  // qt: 0..7
  const int t = threadIdx.x;
  const int w = t >> 6, lane = t & 63, l15 = lane & 15, quad = lane >> 4;
  const size_t hb = (size_t)(b * 8 + h);
  const f32x4 z4 = {0.f, 0.f, 0.f, 0.f};
  __shared__ short Ks[256 * 32];  // [sk][d], 16B-chunk col ^ ((sk>>1)&3)
  __shared__ short Vs[32 * 256];  // [dv][sk_loc], 16B-chunk col ^ (dv&15)

  const int q0 = qt * 128 + w * 32;
  const short8 bq0 = *(const short8*)(Qb + (hb * 1024 + q0 + l15) * 32 + quad * 8);
  const short8 bq1 = *(const short8*)(Qb + (hb * 1024 + q0 + 16 + l15) * 32 + quad * 8);
  const short* Kg = Kb + hb * 1024 * 32;
  const short* Vg = Vb + hb * 32 * 1024;

  short8 ones;
#pragma unroll
  for (int i = 0; i < 8; ++i) ones[i] = (short)0x3F80;  // bf16 1.0

  const int rk_off = lane >> 2;
  const int ck = lane & 3;
  const int rv_off = lane >> 5;
  const int cv = lane & 31;
  const int kread = l15 * 32 + ((quad ^ ((l15 >> 1) & 3)) * 8);

  f32x4 accO[2][2];  // [sq-block][dvt]
  accO[0][0] = z4; accO[0][1] = z4; accO[1][0] = z4; accO[1][1] = z4;
  f32x4 accL[2];
  accL[0] = z4; accL[1] = z4;

  for (int k0 = 0; k0 < 1024; k0 += 256) {
    __syncthreads();
    for (int p = 0; p < 4; ++p) {
      const int rk = (w * 4 + p) * 16 + rk_off;
      load_lds16(Kg + (size_t)(k0 + rk) * 32 + ((ck ^ ((rk >> 1) & 3)) * 8),
                 &Ks[(w * 4 + p) * 512]);
      const int rv = (w * 4 + p) * 2 + rv_off;
      load_lds16(Vg + (size_t)rv * 1024 + k0 + ((cv ^ (rv & 15)) * 8),
                 &Vs[(w * 4 + p) * 512]);
    }
    __syncthreads();

    for (int pr = 0; pr < 8; ++pr) {
      const short8 ak0 = *(const short8*)&Ks[(2 * pr) * 512 + kread];
      const short8 ak1 = *(const short8*)&Ks[(2 * pr + 1) * 512 + kread];
      // scores for both sq-blocks
      f32x4 st00 = MFMA16(ak0, bq0, z4);
      f32x4 st10 = MFMA16(ak1, bq0, z4);
      f32x4 st01 = MFMA16(ak0, bq1, z4);
      f32x4 st11 = MFMA16(ak1, bq1, z4);
      union { short8 s; uint4_ u; } apv0, apv1;
      {
        float p0 = fast_exp2(st00[0]), p1 = fast_exp2(st00[1]);
        float p2 = fast_exp2(st00[2]), p3 = fast_exp2(st00[3]);
        float p4 = fast_exp2(st10[0]), p5 = fast_exp2(st10[1]);
        float p6 = fast_exp2(st10[2]), p7 = fast_exp2(st10[3]);
        apv0.u[0] = pktrunc(p0, p1); apv0.u[1] = pktrunc(p2, p3);
        apv0.u[2] = pktrunc(p4, p5); apv0.u[3] = pktrunc(p6, p7);
      }
      {
        float p0 = fast_exp2(st01[0]), p1 = fast_exp2(st01[1]);
        float p2 = fast_exp2(st01[2]), p3 = fast_exp2(st01[3]);
        float p4 = fast_exp2(st11[0]), p5 = fast_exp2(st11[1]);
        float p6 = fast_exp2(st11[2]), p7 = fast_exp2(st11[3]);
        apv1.u[0] = pktrunc(p0, p1); apv1.u[1] = pktrunc(p2, p3);
        apv1.u[2] = pktrunc(p4, p5); apv1.u[3] = pktrunc(p6, p7);
      }
      const int cg = pr * 4 + (quad >> 1);
      const int so = (quad & 1) * 4;
      for (int dvt = 0; dvt < 2; ++dvt) {
        const int dvrow = (dvt * 16 + l15) * 256;
        union { short8 s; short4_ hh[2]; } bv;
        bv.hh[0] = *(const short4_*)&Vs[dvrow + ((cg ^ l15) * 8) + so];
        bv.hh[1] = *(const short4_*)&Vs[dvrow + (((cg + 2) ^ l15) * 8) + so];
        accO[0][dvt] = MFMA16(apv0.s, bv.s, accO[0][dvt]);
        accO[1][dvt] = MFMA16(apv1.s, bv.s, accO[1][dvt]);
      }
      accL[0] = MFMA16(apv0.s, ones, accL[0]);
      accL[1] = MFMA16(apv1.s, ones, accL[1]);
    }
  }

  for (int s = 0; s < 2; ++s) {
    for (int r = 0; r < 4; r++) {
      float inv = 1.0f / accL[s][r];
      int sq = q0 + s * 16 + quad * 4 + r;
      short* orow = AO + ((size_t)b * 1024 + sq) * 256 + h * 32 + l15;
      orow[0] = f2bf(accO[s][0][r] * inv);
      orow[16] = f2bf(accO[s][1][r] * inv);
    }
  }
}

// ---------------------------------------------------------------------------
// Output GEMM: out[b,m,n] = sum_k Wob[m,k]*ao[b,n,k] + bias[m] + norm[b,m,n]
// ---------------------------------------------------------------------------
__global__ __launch_bounds__(256) void gemm_out_kernel(const short* __restrict__ Wob,
                                                       const short* __restrict__ ao,
                                                       const float* __restrict__ bias,
                                                       const short* __restrict__ Xt,
                                                       float* __restrict__ out) {
  const int m0 = blockIdx.x * 128, n0 = blockIdx.y * 128, b = blockIdx.z;
  const int t = threadIdx.x;
  __shared__ short smem[128 * 64 * 2];
  short* As = smem;
  short* Bs = smem + 128 * 64;
  const int w = t >> 6, lane = t & 63, l15 = lane & 15, quad = lane >> 4;
  const int wm = (w >> 1) * 64, wn = (w & 1) * 64;
  const f32x4 z4 = {0.f, 0.f, 0.f, 0.f};
  f32x4 acc[4][4];
  for (int i = 0; i < 4; i++)
    for (int j = 0; j < 4; j++) acc[i][j] = z4;

  const int srow = lane >> 3, cpos = lane & 7;
  const int swz = (cpos ^ srow) * 8;
  const short* wg = Wob + (size_t)(m0 + w * 32 + srow) * 256 + swz;
  const short* xg = ao + ((size_t)b * 1024 + n0 + w * 32 + srow) * 256 + swz;
  short* lA = &As[(w * 32) * 64];
  short* lB = &Bs[(w * 32) * 64];

  for (int k0 = 0; k0 < 256; k0 += 64) {
    __syncthreads();
#pragma unroll
    for (int qq = 0; qq < 4; ++qq) {
      load_lds16(wg + (size_t)qq * 8 * 256 + k0, lA + qq * 8 * 64);
      load_lds16(xg + (size_t)qq * 8 * 256 + k0, lB + qq * 8 * 64);
    }
    __syncthreads();
#pragma unroll
    for (int s = 0; s < 2; ++s) {
      const int cc = ((s * 4 + quad) ^ (l15 & 7)) * 8;
      short8 af[4], bfb[4];
      for (int i = 0; i < 4; i++) af[i] = *(const short8*)&As[(wm + i * 16 + l15) * 64 + cc];
      for (int j = 0; j < 4; j++) bfb[j] = *(const short8*)&Bs[(wn + j * 16 + l15) * 64 + cc];
      for (int i = 0; i < 4; i++)
        for (int j = 0; j < 4; j++) acc[i][j] = MFMA16(af[i], bfb[j], acc[i][j]);
    }
  }

  __syncthreads();
  {
    const int rrow = lane >> 4, rc = lane & 15;
    for (int qq = 0; qq < 8; ++qq) {
      int row = w * 32 + qq * 4 + rrow;
      load_lds16(Xt + ((size_t)b * 1024 + n0 + row) * 256 + m0 + ((rc ^ (row & 15)) * 8),
                 &smem[(w * 32 + qq * 4) * 128]);
    }
  }
  __syncthreads();

  for (int i = 0; i < 4; i++)
    for (int j = 0; j < 4; j++) {
      int m = m0 + wm + i * 16 + quad * 4;
      int nl = wn + j * 16 + l15;
      int n = n0 + nl;
      size_t off = ((size_t)b * 256 + m) * 1024 + n;
      const int chunk = (wm >> 3) + i * 2 + (quad >> 1);
      short4_ rv = *(const short4_*)&smem[nl * 128 + ((chunk ^ (nl & 15)) * 8) + (quad & 1) * 4];
      for (int r = 0; r < 4; r++)
        out[off + (size_t)r * 1024] = acc[i][j][r] + bias[m + r] + bf2f(rv[r]);
    }
}

// ---------------------------------------------------------------------------
extern "C" void kernel_launch(void* const* d_in, const int* in_sizes, int n_in,
                              void* d_out, int out_size, void* d_ws, size_t ws_size,
                              hipStream_t stream) {
  const float* xA = (const float*)d_in[0];
  const float* xB = (const float*)d_in[1];
  const float* gA = (const float*)d_in[2];
  const float* bA = (const float*)d_in[3];
  const float* gB = (const float*)d_in[4];
  const float* bB = (const float*)d_in[5];
  const float* WqkvA = (const float*)d_in[6];
  const float* WqkvB = (const float*)d_in[7];
  const float* WoutA = (const float*)d_in[8];
  const float* boutA = (const float*)d_in[9];
  const float* WoutB = (const float*)d_in[10];
  const float* boutB = (const float*)d_in[11];
  float* out = (float*)d_out;
  char* ws = (char*)d_ws;
  short* XtA = (short*)(ws);                   // 8 MB bf16 norm A [b,s,c]
  short* XtB = (short*)(ws + 8388608);         // 8 MB bf16 norm B [b,s,c]
  short* QbA = (short*)(ws + 16777216);        // 8 MB [b,h,s,d] (pre-scaled)
  short* KbA = (short*)(ws + 25165824);
  short* VbA = (short*)(ws + 33554432);        // [b,h,d,s]
  short* QbB = (short*)(ws + 41943040);
  short* KbB = (short*)(ws + 50331648);
  short* VbB = (short*)(ws + 58720256);
  short* aoA = (short*)(ws + 67108864);        // 8 MB attn-out A [b,s,c]
  short* aoB = (short*)(ws + 75497472);
  short* WqbA = (short*)(ws + 83886080);       // 384 KB
  short* WqbB = (short*)(ws + 84279296);
  short* WobA = (short*)(ws + 84672512);       // 128 KB
  short* WobB = (short*)(ws + 84803584);

  wcvt_kernel<<<256, 256, 0, stream>>>(WqkvA, WqkvB, WoutA, WoutB, WqbA, WqbB, WobA, WobB);
  gn_kernel<<<256, 256, 0, stream>>>(xA, gA, bA, XtA);
  gn_kernel<<<256, 256, 0, stream>>>(xB, gB, bB, XtB);
  gemm_qkv_kernel<<<dim3(6, 8, 16), 256, 0, stream>>>(WqbA, XtA, QbA, KbA, VbA);
  gemm_qkv_kernel<<<dim3(6, 8, 16), 256, 0, stream>>>(WqbB, XtB, QbB, KbB, VbB);
  // branch A output: attn(qB -> kA,vA); branch B: attn(qA -> kB,vB)
  attn_kernel<<<dim3(8, 8, 16), 256, 0, stream>>>(QbB, KbA, VbA, aoA);
  attn_kernel<<<dim3(8, 8, 16), 256, 0, stream>>>(QbA, KbB, VbB, aoB);
  gemm_out_kernel<<<dim3(2, 8, 16), 256, 0, stream>>>(WobA, aoA, boutA, XtA, out);
  gemm_out_kernel<<<dim3(2, 8, 16), 256, 0, stream>>>(WobB, aoB, boutB, XtB, out + 4194304);
}

// Round 7
// 195.150 us; speedup vs baseline: 2.8478x; 1.1613x over previous
//
#include <hip/hip_runtime.h>
#include <hip/hip_bf16.h>
#include <math.h>

typedef __attribute__((ext_vector_type(8))) short short8;
typedef __attribute__((ext_vector_type(4))) short short4_;
typedef __attribute__((ext_vector_type(4))) float f32x4;
typedef __attribute__((ext_vector_type(4))) unsigned int uint4_;

#define MFMA16(a, b, c) __builtin_amdgcn_mfma_f32_16x16x32_bf16((a), (b), (c), 0, 0, 0)

// workspace byte offsets
#define OFF_XTA   0
#define OFF_XTB   8388608
#define OFF_QBA   16777216
#define OFF_KBA   25165824
#define OFF_VBA   33554432
#define OFF_QBB   41943040
#define OFF_KBB   50331648
#define OFF_VBB   58720256
#define OFF_AOA   67108864
#define OFF_AOB   75497472
#define OFF_WQA   83886080
#define OFF_WQB   84279296
#define OFF_WOA   84672512
#define OFF_WOB   84803584

// fp32 -> bf16 round-to-nearest-even (scalar)
__device__ __forceinline__ short f2bf(float f) {
  union { float f; unsigned u; } v; v.f = f;
  unsigned r = v.u + 0x7fffu + ((v.u >> 16) & 1u);
  return (short)(r >> 16);
}

__device__ __forceinline__ float bf2f(short s) {
  union { float f; unsigned u; } v; v.u = ((unsigned)(unsigned short)s) << 16;
  return v.f;
}

// pack two fp32 -> 2x bf16 RNE in one v_cvt_pk_bf16_f32: a -> low, b -> high
__device__ __forceinline__ unsigned pk2bf(float a, float b) {
  union { __hip_bfloat162 h2; unsigned u; } cv;
  cv.h2 = __float22bfloat162_rn(float2{a, b});
  return cv.u;
}

// pack two fp32 -> 2x bf16 TRUNCATED (v_perm_b32), for attention P
__device__ __forceinline__ unsigned pktrunc(float a, float b) {
#if __has_builtin(__builtin_amdgcn_perm)
  return __builtin_amdgcn_perm(__builtin_bit_cast(unsigned, b),
                               __builtin_bit_cast(unsigned, a), 0x07060302u);
#else
  return (__builtin_bit_cast(unsigned, b) & 0xffff0000u) |
         (__builtin_bit_cast(unsigned, a) >> 16);
#endif
}

__device__ __forceinline__ float fast_exp2(float x) {
#if __has_builtin(__builtin_amdgcn_exp2f)
  return __builtin_amdgcn_exp2f(x);
#else
  return __exp2f(x);
#endif
}

// async global -> LDS, 16 B per lane; LDS dest = base + lane*16 (base wave-uniform)
__device__ __forceinline__ void load_lds16(const void* g, void* l) {
  __builtin_amdgcn_global_load_lds((const __attribute__((address_space(1))) void*)g,
                                   (__attribute__((address_space(3))) void*)l, 16, 0, 0);
}

// scale(1/sqrt(256)) * log2(e), folded into Q values at the QKV GEMM epilogue
#define QSCALE 0.09016844005556f

// ---------------------------------------------------------------------------
// Prep: blocks 0..511 GroupNorm (A then B); blocks 512..767 weight convert.
// GroupNorm: block=(br,b,g); thread t holds 16-ch column for s=4t..4t+3 ->
// register transpose -> bf16 Xt[b,s,c] via packed cvt.
// ---------------------------------------------------------------------------
__global__ __launch_bounds__(256) void prep_kernel(const float* __restrict__ xA,
                                                   const float* __restrict__ xB,
                                                   const float* __restrict__ gA,
                                                   const float* __restrict__ bA,
                                                   const float* __restrict__ gB,
                                                   const float* __restrict__ bB,
                                                   const float* __restrict__ wqA,
                                                   const float* __restrict__ wqB,
                                                   const float* __restrict__ woA,
                                                   const float* __restrict__ woB,
                                                   char* __restrict__ ws) {
  const int blk = blockIdx.x;
  const int t = threadIdx.x;
  if (blk >= 512) {  // weight convert
    int wb = blk - 512;
    const float* src; short* dst; int base;
    if (wb < 96) { src = wqA; dst = (short*)(ws + OFF_WQA); base = wb; }
    else if (wb < 192) { src = wqB; dst = (short*)(ws + OFF_WQB); base = wb - 96; }
    else if (wb < 224) { src = woA; dst = (short*)(ws + OFF_WOA); base = wb - 192; }
    else { src = woB; dst = (short*)(ws + OFF_WOB); base = wb - 224; }
    int idx = base * 2048 + t * 8;
    float4 a = *(const float4*)(src + idx);
    float4 b = *(const float4*)(src + idx + 4);
    uint4_ o;
    o[0] = pk2bf(a.x, a.y); o[1] = pk2bf(a.z, a.w);
    o[2] = pk2bf(b.x, b.y); o[3] = pk2bf(b.z, b.w);
    *(uint4_*)(dst + idx) = o;
    return;
  }
  const int br = blk >> 8, sub = blk & 255;
  const int b = sub >> 4, g = sub & 15;
  const float* x = br ? xB : xA;
  const float* gamma = br ? gB : gA;
  const float* beta = br ? bB : bA;
  short* Xt = (short*)(ws + (br ? OFF_XTB : OFF_XTA));
  const size_t base = (size_t)sub * 16384;
  const float4* xp = (const float4*)(x + base);
  float s = 0.f, q = 0.f;
  float4 vals[16];
  for (int i = 0; i < 16; ++i) {
    float4 v = xp[t + i * 256];  // channel g*16+i, s = 4t..4t+3
    vals[i] = v;
    s += v.x + v.y + v.z + v.w;
    q += v.x * v.x + v.y * v.y + v.z * v.z + v.w * v.w;
  }
  __shared__ float rs[256], rq[256];
  rs[t] = s; rq[t] = q;
  __syncthreads();
  for (int o = 128; o > 0; o >>= 1) {
    if (t < o) { rs[t] += rs[t + o]; rq[t] += rq[t + o]; }
    __syncthreads();
  }
  __shared__ float sh_mu, sh_inv;
  if (t == 0) {
    float mu = rs[0] * (1.f / 16384.f);
    float var = rq[0] * (1.f / 16384.f) - mu * mu;
    sh_mu = mu;
    sh_inv = rsqrtf(var + 1e-5f);
  }
  __syncthreads();
  const float mu = sh_mu, inv = sh_inv;
  unsigned td[4][8];
#pragma unroll
  for (int i = 0; i < 16; i += 2) {
    int c = (g << 4) + i;
    float ga0 = gamma[c] * inv, be0 = beta[c] - mu * ga0;
    float ga1 = gamma[c + 1] * inv, be1 = beta[c + 1] - mu * ga1;
    float4 v0 = vals[i], v1 = vals[i + 1];
    td[0][i >> 1] = pk2bf(v0.x * ga0 + be0, v1.x * ga1 + be1);
    td[1][i >> 1] = pk2bf(v0.y * ga0 + be0, v1.y * ga1 + be1);
    td[2][i >> 1] = pk2bf(v0.z * ga0 + be0, v1.z * ga1 + be1);
    td[3][i >> 1] = pk2bf(v0.w * ga0 + be0, v1.w * ga1 + be1);
  }
  short* orow = Xt + ((size_t)b * 1024 + 4 * t) * 256 + (g << 4);
#pragma unroll
  for (int j = 0; j < 4; ++j) {
    *(uint4_*)(orow + j * 256) = *(const uint4_*)&td[j][0];
    *(uint4_*)(orow + j * 256 + 8) = *(const uint4_*)&td[j][4];
  }
}

// ---------------------------------------------------------------------------
// QKV GEMM, both branches. Grid (nt=8, mt=6, z=b+16*br). Xt-tile sharers have
// linear-index stride 8 -> same XCD (L2 reuse). BK=64, global_load_lds.
// Epilogue: Q->[b,h,s,d]*QSCALE, K->[b,h,s,d], V->[b,h,d,s].
// ---------------------------------------------------------------------------
__global__ __launch_bounds__(256) void gemm_qkv_kernel(char* __restrict__ ws) {
  const int n0 = blockIdx.x * 128, m0 = blockIdx.y * 128;
  const int b = blockIdx.z & 15, br = blockIdx.z >> 4;
  const short* Wb = (const short*)(ws + (br ? OFF_WQB : OFF_WQA));
  const short* Xt = (const short*)(ws + (br ? OFF_XTB : OFF_XTA));
  short* Qb = (short*)(ws + (br ? OFF_QBB : OFF_QBA));
  short* Kb = Qb + 4194304;
  short* Vb = Qb + 8388608;
  const int t = threadIdx.x;
  __shared__ short As[128 * 64];
  __shared__ short Bs[128 * 64];
  const int w = t >> 6, lane = t & 63, l15 = lane & 15, quad = lane >> 4;
  const int wm = (w >> 1) * 64, wn = (w & 1) * 64;
  const f32x4 z4 = {0.f, 0.f, 0.f, 0.f};
  f32x4 acc[4][4];
  for (int i = 0; i < 4; i++)
    for (int j = 0; j < 4; j++) acc[i][j] = z4;

  const int srow = lane >> 3, cpos = lane & 7;
  const int swz = (cpos ^ srow) * 8;
  const short* wg = Wb + (size_t)(m0 + w * 32 + srow) * 256 + swz;
  const short* xg = Xt + ((size_t)b * 1024 + n0 + w * 32 + srow) * 256 + swz;
  short* lA = &As[(w * 32) * 64];
  short* lB = &Bs[(w * 32) * 64];

  for (int k0 = 0; k0 < 256; k0 += 64) {
    __syncthreads();
#pragma unroll
    for (int qq = 0; qq < 4; ++qq) {
      load_lds16(wg + (size_t)qq * 8 * 256 + k0, lA + qq * 8 * 64);
      load_lds16(xg + (size_t)qq * 8 * 256 + k0, lB + qq * 8 * 64);
    }
    __syncthreads();
#pragma unroll
    for (int s = 0; s < 2; ++s) {
      const int cc = ((s * 4 + quad) ^ (l15 & 7)) * 8;
      short8 af[4], bfb[4];
      for (int i = 0; i < 4; i++) af[i] = *(const short8*)&As[(wm + i * 16 + l15) * 64 + cc];
      for (int j = 0; j < 4; j++) bfb[j] = *(const short8*)&Bs[(wn + j * 16 + l15) * 64 + cc];
      for (int i = 0; i < 4; i++)
        for (int j = 0; j < 4; j++) acc[i][j] = MFMA16(af[i], bfb[j], acc[i][j]);
    }
  }
  for (int i = 0; i < 4; i++) {
    int mi = m0 + wm + i * 16;
    int h = mi / 96;
    int rr = mi - h * 96;
    if (rr < 64) {  // q or k: [b,h,s,d]
      short* dst = (rr < 32) ? Qb : Kb;
      const float mul = (rr < 32) ? QSCALE : 1.0f;
      const int dbase = (rr & 31) + quad * 4;
      const size_t rowb = ((size_t)b * 8 + h) * 1024;
      for (int j = 0; j < 4; j++) {
        int n = n0 + wn + j * 16 + l15;
        union { unsigned u[2]; short4_ s; } uv;
        uv.u[0] = pk2bf(acc[i][j][0] * mul, acc[i][j][1] * mul);
        uv.u[1] = pk2bf(acc[i][j][2] * mul, acc[i][j][3] * mul);
        *(short4_*)(dst + (rowb + n) * 32 + dbase) = uv.s;
      }
    } else {  // v: [b,h,d,s]
      const int dv = (rr - 64) + quad * 4;
      const size_t vb = (((size_t)b * 8 + h) * 32 + dv) * 1024;
      for (int j = 0; j < 4; j++) {
        int n = n0 + wn + j * 16 + l15;
        for (int r = 0; r < 4; r++) Vb[vb + (size_t)r * 1024 + n] = f2bf(acc[i][j][r]);
      }
    }
  }
}

// ---------------------------------------------------------------------------
// Flash cross-attention, both branches. Grid (b=16, h=8, z=qt+8*br): the 8
// qt-blocks sharing one (b,h)'s K/V have linear stride 128 -> same XCD.
// Block = 128 queries; wave owns two 16-q blocks. 256-key LDS tiles via
// global_load_lds (XOR-swizzled). S^T=MFMA(A=K,B=Q); P bf16-truncated
// (v_perm); l via ones-MFMA.
// ---------------------------------------------------------------------------
__global__ __launch_bounds__(256) void attn_kernel(char* __restrict__ ws) {
  const int b = blockIdx.x, h = blockIdx.y;
  const int qt = blockIdx.z & 7, br = blockIdx.z >> 3;
  // branch A output (br=0) uses Q from B, K/V from A; br=1 mirrored
  const short* Qb = (const short*)(ws + (br ? OFF_QBA : OFF_QBB));
  const short* Kb = (const short*)(ws + (br ? OFF_KBB : OFF_KBA));
  const short* Vb = Kb + 4194304;
  short* AO = (short*)(ws + (br ? OFF_AOB : OFF_AOA));
  const int t = threadIdx.x;
  const int w = t >> 6, lane = t & 63, l15 = lane & 15, quad = lane >> 4;
  const size_t hb = (size_t)(b * 8 + h);
  const f32x4 z4 = {0.f, 0.f, 0.f, 0.f};
  __shared__ short Ks[256 * 32];  // [sk][d], 16B-chunk col ^ ((sk>>1)&3)
  __shared__ short Vs[32 * 256];  // [dv][sk_loc], 16B-chunk col ^ (dv&15)

  const int q0 = qt * 128 + w * 32;
  const short8 bq0 = *(const short8*)(Qb + (hb * 1024 + q0 + l15) * 32 + quad * 8);
  const short8 bq1 = *(const short8*)(Qb + (hb * 1024 + q0 + 16 + l15) * 32 + quad * 8);
  const short* Kg = Kb + hb * 1024 * 32;
  const short* Vg = Vb + hb * 32 * 1024;

  short8 ones;
#pragma unroll
  for (int i = 0; i < 8; ++i) ones[i] = (short)0x3F80;  // bf16 1.0

  const int rk_off = lane >> 2;
  const int ck = lane & 3;
  const int rv_off = lane >> 5;
  const int cv = lane & 31;
  const int kread = l15 * 32 + ((quad ^ ((l15 >> 1) & 3)) * 8);

  f32x4 accO[2][2];  // [sq-block][dvt]
  accO[0][0] = z4; accO[0][1] = z4; accO[1][0] = z4; accO[1][1] = z4;
  f32x4 accL[2];
  accL[0] = z4; accL[1] = z4;

  for (int k0 = 0; k0 < 1024; k0 += 256) {
    __syncthreads();
    for (int p = 0; p < 4; ++p) {
      const int rk = (w * 4 + p) * 16 + rk_off;
      load_lds16(Kg + (size_t)(k0 + rk) * 32 + ((ck ^ ((rk >> 1) & 3)) * 8),
                 &Ks[(w * 4 + p) * 512]);
      const int rv = (w * 4 + p) * 2 + rv_off;
      load_lds16(Vg + (size_t)rv * 1024 + k0 + ((cv ^ (rv & 15)) * 8),
                 &Vs[(w * 4 + p) * 512]);
    }
    __syncthreads();

    for (int pr = 0; pr < 8; ++pr) {
      const short8 ak0 = *(const short8*)&Ks[(2 * pr) * 512 + kread];
      const short8 ak1 = *(const short8*)&Ks[(2 * pr + 1) * 512 + kread];
      f32x4 st00 = MFMA16(ak0, bq0, z4);
      f32x4 st10 = MFMA16(ak1, bq0, z4);
      f32x4 st01 = MFMA16(ak0, bq1, z4);
      f32x4 st11 = MFMA16(ak1, bq1, z4);
      union { short8 s; uint4_ u; } apv0, apv1;
      {
        float p0 = fast_exp2(st00[0]), p1 = fast_exp2(st00[1]);
        float p2 = fast_exp2(st00[2]), p3 = fast_exp2(st00[3]);
        float p4 = fast_exp2(st10[0]), p5 = fast_exp2(st10[1]);
        float p6 = fast_exp2(st10[2]), p7 = fast_exp2(st10[3]);
        apv0.u[0] = pktrunc(p0, p1); apv0.u[1] = pktrunc(p2, p3);
        apv0.u[2] = pktrunc(p4, p5); apv0.u[3] = pktrunc(p6, p7);
      }
      {
        float p0 = fast_exp2(st01[0]), p1 = fast_exp2(st01[1]);
        float p2 = fast_exp2(st01[2]), p3 = fast_exp2(st01[3]);
        float p4 = fast_exp2(st11[0]), p5 = fast_exp2(st11[1]);
        float p6 = fast_exp2(st11[2]), p7 = fast_exp2(st11[3]);
        apv1.u[0] = pktrunc(p0, p1); apv1.u[1] = pktrunc(p2, p3);
        apv1.u[2] = pktrunc(p4, p5); apv1.u[3] = pktrunc(p6, p7);
      }
      const int cg = pr * 4 + (quad >> 1);
      const int so = (quad & 1) * 4;
      for (int dvt = 0; dvt < 2; ++dvt) {
        const int dvrow = (dvt * 16 + l15) * 256;
        union { short8 s; short4_ hh[2]; } bv;
        bv.hh[0] = *(const short4_*)&Vs[dvrow + ((cg ^ l15) * 8) + so];
        bv.hh[1] = *(const short4_*)&Vs[dvrow + (((cg + 2) ^ l15) * 8) + so];
        accO[0][dvt] = MFMA16(apv0.s, bv.s, accO[0][dvt]);
        accO[1][dvt] = MFMA16(apv1.s, bv.s, accO[1][dvt]);
      }
      accL[0] = MFMA16(apv0.s, ones, accL[0]);
      accL[1] = MFMA16(apv1.s, ones, accL[1]);
    }
  }

  for (int s = 0; s < 2; ++s) {
    for (int r = 0; r < 4; r++) {
      float inv = 1.0f / accL[s][r];
      int sq = q0 + s * 16 + quad * 4 + r;
      short* orow = AO + ((size_t)b * 1024 + sq) * 256 + h * 32 + l15;
      orow[0] = f2bf(accO[s][0][r] * inv);
      orow[16] = f2bf(accO[s][1][r] * inv);
    }
  }
}

// ---------------------------------------------------------------------------
// Output GEMM, both branches: out[b,m,n] = sum_k Wob[m,k]*ao[b,n,k] + bias[m]
// + norm[b,m,n]. Grid (mt=2, nt=8, z=b+16*br).
// ---------------------------------------------------------------------------
__global__ __launch_bounds__(256) void gemm_out_kernel(char* __restrict__ ws,
                                                       const float* __restrict__ boutA,
                                                       const float* __restrict__ boutB,
                                                       float* __restrict__ outbase) {
  const int m0 = blockIdx.x * 128, n0 = blockIdx.y * 128;
  const int b = blockIdx.z & 15, br = blockIdx.z >> 4;
  const short* Wob = (const short*)(ws + (br ? OFF_WOB : OFF_WOA));
  const short* ao = (const short*)(ws + (br ? OFF_AOB : OFF_AOA));
  const float* bias = br ? boutB : boutA;
  const short* Xt = (const short*)(ws + (br ? OFF_XTB : OFF_XTA));
  float* out = outbase + (br ? 4194304 : 0);
  const int t = threadIdx.x;
  __shared__ short smem[128 * 64 * 2];
  short* As = smem;
  short* Bs = smem + 128 * 64;
  const int w = t >> 6, lane = t & 63, l15 = lane & 15, quad = lane >> 4;
  const int wm = (w >> 1) * 64, wn = (w & 1) * 64;
  const f32x4 z4 = {0.f, 0.f, 0.f, 0.f};
  f32x4 acc[4][4];
  for (int i = 0; i < 4; i++)
    for (int j = 0; j < 4; j++) acc[i][j] = z4;

  const int srow = lane >> 3, cpos = lane & 7;
  const int swz = (cpos ^ srow) * 8;
  const short* wg = Wob + (size_t)(m0 + w * 32 + srow) * 256 + swz;
  const short* xg = ao + ((size_t)b * 1024 + n0 + w * 32 + srow) * 256 + swz;
  short* lA = &As[(w * 32) * 64];
  short* lB = &Bs[(w * 32) * 64];

  for (int k0 = 0; k0 < 256; k0 += 64) {
    __syncthreads();
#pragma unroll
    for (int qq = 0; qq < 4; ++qq) {
      load_lds16(wg + (size_t)qq * 8 * 256 + k0, lA + qq * 8 * 64);
      load_lds16(xg + (size_t)qq * 8 * 256 + k0, lB + qq * 8 * 64);
    }
    __syncthreads();
#pragma unroll
    for (int s = 0; s < 2; ++s) {
      const int cc = ((s * 4 + quad) ^ (l15 & 7)) * 8;
      short8 af[4], bfb[4];
      for (int i = 0; i < 4; i++) af[i] = *(const short8*)&As[(wm + i * 16 + l15) * 64 + cc];
      for (int j = 0; j < 4; j++) bfb[j] = *(const short8*)&Bs[(wn + j * 16 + l15) * 64 + cc];
      for (int i = 0; i < 4; i++)
        for (int j = 0; j < 4; j++) acc[i][j] = MFMA16(af[i], bfb[j], acc[i][j]);
    }
  }

  __syncthreads();
  {
    const int rrow = lane >> 4, rc = lane & 15;
    for (int qq = 0; qq < 8; ++qq) {
      int row = w * 32 + qq * 4 + rrow;
      load_lds16(Xt + ((size_t)b * 1024 + n0 + row) * 256 + m0 + ((rc ^ (row & 15)) * 8),
                 &smem[(w * 32 + qq * 4) * 128]);
    }
  }
  __syncthreads();

  for (int i = 0; i < 4; i++)
    for (int j = 0; j < 4; j++) {
      int m = m0 + wm + i * 16 + quad * 4;
      int nl = wn + j * 16 + l15;
      int n = n0 + nl;
      size_t off = ((size_t)b * 256 + m) * 1024 + n;
      const int chunk = (wm >> 3) + i * 2 + (quad >> 1);
      short4_ rv = *(const short4_*)&smem[nl * 128 + ((chunk ^ (nl & 15)) * 8) + (quad & 1) * 4];
      for (int r = 0; r < 4; r++)
        out[off + (size_t)r * 1024] = acc[i][j][r] + bias[m + r] + bf2f(rv[r]);
    }
}

// ---------------------------------------------------------------------------
extern "C" void kernel_launch(void* const* d_in, const int* in_sizes, int n_in,
                              void* d_out, int out_size, void* d_ws, size_t ws_size,
                              hipStream_t stream) {
  const float* xA = (const float*)d_in[0];
  const float* xB = (const float*)d_in[1];
  const float* gA = (const float*)d_in[2];
  const float* bA = (const float*)d_in[3];
  const float* gB = (const float*)d_in[4];
  const float* bB = (const float*)d_in[5];
  const float* WqkvA = (const float*)d_in[6];
  const float* WqkvB = (const float*)d_in[7];
  const float* WoutA = (const float*)d_in[8];
  const float* boutA = (const float*)d_in[9];
  const float* WoutB = (const float*)d_in[10];
  const float* boutB = (const float*)d_in[11];
  float* out = (float*)d_out;
  char* ws = (char*)d_ws;

  prep_kernel<<<768, 256, 0, stream>>>(xA, xB, gA, bA, gB, bB,
                                       WqkvA, WqkvB, WoutA, WoutB, ws);
  gemm_qkv_kernel<<<dim3(8, 6, 32), 256, 0, stream>>>(ws);
  attn_kernel<<<dim3(16, 8, 16), 256, 0, stream>>>(ws);
  gemm_out_kernel<<<dim3(2, 8, 32), 256, 0, stream>>>(ws, boutA, boutB, out);
}

// Round 8
// 182.871 us; speedup vs baseline: 3.0390x; 1.0671x over previous
//
#include <hip/hip_runtime.h>
#include <hip/hip_bf16.h>
#include <math.h>

typedef __attribute__((ext_vector_type(8))) short short8;
typedef __attribute__((ext_vector_type(4))) short short4_;
typedef __attribute__((ext_vector_type(4))) float f32x4;
typedef __attribute__((ext_vector_type(4))) unsigned int uint4_;

#define MFMA16(a, b, c) __builtin_amdgcn_mfma_f32_16x16x32_bf16((a), (b), (c), 0, 0, 0)

// workspace byte offsets
#define OFF_XTA   0
#define OFF_XTB   8388608
#define OFF_QBA   16777216
#define OFF_KBA   25165824
#define OFF_VBA   33554432
#define OFF_QBB   41943040
#define OFF_KBB   50331648
#define OFF_VBB   58720256
#define OFF_AOA   67108864
#define OFF_AOB   75497472
#define OFF_WQA   83886080
#define OFF_WQB   84279296
#define OFF_WOA   84672512
#define OFF_WOB   84803584

// fp32 -> bf16 round-to-nearest-even (scalar)
__device__ __forceinline__ short f2bf(float f) {
  union { float f; unsigned u; } v; v.f = f;
  unsigned r = v.u + 0x7fffu + ((v.u >> 16) & 1u);
  return (short)(r >> 16);
}

__device__ __forceinline__ float bf2f(short s) {
  union { float f; unsigned u; } v; v.u = ((unsigned)(unsigned short)s) << 16;
  return v.f;
}

// pack two fp32 -> 2x bf16 RNE in one v_cvt_pk_bf16_f32: a -> low, b -> high
__device__ __forceinline__ unsigned pk2bf(float a, float b) {
  union { __hip_bfloat162 h2; unsigned u; } cv;
  cv.h2 = __float22bfloat162_rn(float2{a, b});
  return cv.u;
}

// pack two fp32 -> 2x bf16 TRUNCATED (v_perm_b32), for attention P
__device__ __forceinline__ unsigned pktrunc(float a, float b) {
#if __has_builtin(__builtin_amdgcn_perm)
  return __builtin_amdgcn_perm(__builtin_bit_cast(unsigned, b),
                               __builtin_bit_cast(unsigned, a), 0x07060302u);
#else
  return (__builtin_bit_cast(unsigned, b) & 0xffff0000u) |
         (__builtin_bit_cast(unsigned, a) >> 16);
#endif
}

// Schraudolph-style exp2: full-rate (fma + cvt_i32), max rel err ~3%.
// Errors cancel in softmax: numerator and denominator use the same P.
__device__ __forceinline__ float approx_exp2(float x) {
  int i = (int)__builtin_fmaf(x, 8388608.0f, 1064991921.0f);
  return __builtin_bit_cast(float, i);
}

// async global -> LDS, 16 B per lane; LDS dest = base + lane*16 (base wave-uniform)
__device__ __forceinline__ void load_lds16(const void* g, void* l) {
  __builtin_amdgcn_global_load_lds((const __attribute__((address_space(1))) void*)g,
                                   (__attribute__((address_space(3))) void*)l, 16, 0, 0);
}

// scale(1/sqrt(256)) * log2(e), folded into Q values at the QKV GEMM epilogue
#define QSCALE 0.09016844005556f

// ---------------------------------------------------------------------------
// Prep: blocks 0..511 GroupNorm (A then B); blocks 512..767 weight convert.
// ---------------------------------------------------------------------------
__global__ __launch_bounds__(256) void prep_kernel(const float* __restrict__ xA,
                                                   const float* __restrict__ xB,
                                                   const float* __restrict__ gA,
                                                   const float* __restrict__ bA,
                                                   const float* __restrict__ gB,
                                                   const float* __restrict__ bB,
                                                   const float* __restrict__ wqA,
                                                   const float* __restrict__ wqB,
                                                   const float* __restrict__ woA,
                                                   const float* __restrict__ woB,
                                                   char* __restrict__ ws) {
  const int blk = blockIdx.x;
  const int t = threadIdx.x;
  if (blk >= 512) {  // weight convert
    int wb = blk - 512;
    const float* src; short* dst; int base;
    if (wb < 96) { src = wqA; dst = (short*)(ws + OFF_WQA); base = wb; }
    else if (wb < 192) { src = wqB; dst = (short*)(ws + OFF_WQB); base = wb - 96; }
    else if (wb < 224) { src = woA; dst = (short*)(ws + OFF_WOA); base = wb - 192; }
    else { src = woB; dst = (short*)(ws + OFF_WOB); base = wb - 224; }
    int idx = base * 2048 + t * 8;
    float4 a = *(const float4*)(src + idx);
    float4 b = *(const float4*)(src + idx + 4);
    uint4_ o;
    o[0] = pk2bf(a.x, a.y); o[1] = pk2bf(a.z, a.w);
    o[2] = pk2bf(b.x, b.y); o[3] = pk2bf(b.z, b.w);
    *(uint4_*)(dst + idx) = o;
    return;
  }
  const int br = blk >> 8, sub = blk & 255;
  const int b = sub >> 4, g = sub & 15;
  const float* x = br ? xB : xA;
  const float* gamma = br ? gB : gA;
  const float* beta = br ? bB : bA;
  short* Xt = (short*)(ws + (br ? OFF_XTB : OFF_XTA));
  const size_t base = (size_t)sub * 16384;
  const float4* xp = (const float4*)(x + base);
  float s = 0.f, q = 0.f;
  float4 vals[16];
  for (int i = 0; i < 16; ++i) {
    float4 v = xp[t + i * 256];  // channel g*16+i, s = 4t..4t+3
    vals[i] = v;
    s += v.x + v.y + v.z + v.w;
    q += v.x * v.x + v.y * v.y + v.z * v.z + v.w * v.w;
  }
  __shared__ float rs[256], rq[256];
  rs[t] = s; rq[t] = q;
  __syncthreads();
  for (int o = 128; o > 0; o >>= 1) {
    if (t < o) { rs[t] += rs[t + o]; rq[t] += rq[t + o]; }
    __syncthreads();
  }
  __shared__ float sh_mu, sh_inv;
  if (t == 0) {
    float mu = rs[0] * (1.f / 16384.f);
    float var = rq[0] * (1.f / 16384.f) - mu * mu;
    sh_mu = mu;
    sh_inv = rsqrtf(var + 1e-5f);
  }
  __syncthreads();
  const float mu = sh_mu, inv = sh_inv;
  unsigned td[4][8];
#pragma unroll
  for (int i = 0; i < 16; i += 2) {
    int c = (g << 4) + i;
    float ga0 = gamma[c] * inv, be0 = beta[c] - mu * ga0;
    float ga1 = gamma[c + 1] * inv, be1 = beta[c + 1] - mu * ga1;
    float4 v0 = vals[i], v1 = vals[i + 1];
    td[0][i >> 1] = pk2bf(v0.x * ga0 + be0, v1.x * ga1 + be1);
    td[1][i >> 1] = pk2bf(v0.y * ga0 + be0, v1.y * ga1 + be1);
    td[2][i >> 1] = pk2bf(v0.z * ga0 + be0, v1.z * ga1 + be1);
    td[3][i >> 1] = pk2bf(v0.w * ga0 + be0, v1.w * ga1 + be1);
  }
  short* orow = Xt + ((size_t)b * 1024 + 4 * t) * 256 + (g << 4);
#pragma unroll
  for (int j = 0; j < 4; ++j) {
    *(uint4_*)(orow + j * 256) = *(const uint4_*)&td[j][0];
    *(uint4_*)(orow + j * 256 + 8) = *(const uint4_*)&td[j][4];
  }
}

// ---------------------------------------------------------------------------
// QKV GEMM, both branches. Grid (nt=8, mt=6, z=b+16*br).
// ---------------------------------------------------------------------------
__global__ __launch_bounds__(256) void gemm_qkv_kernel(char* __restrict__ ws) {
  const int n0 = blockIdx.x * 128, m0 = blockIdx.y * 128;
  const int b = blockIdx.z & 15, br = blockIdx.z >> 4;
  const short* Wb = (const short*)(ws + (br ? OFF_WQB : OFF_WQA));
  const short* Xt = (const short*)(ws + (br ? OFF_XTB : OFF_XTA));
  short* Qb = (short*)(ws + (br ? OFF_QBB : OFF_QBA));
  short* Kb = Qb + 4194304;
  short* Vb = Qb + 8388608;
  const int t = threadIdx.x;
  __shared__ short As[128 * 64];
  __shared__ short Bs[128 * 64];
  const int w = t >> 6, lane = t & 63, l15 = lane & 15, quad = lane >> 4;
  const int wm = (w >> 1) * 64, wn = (w & 1) * 64;
  const f32x4 z4 = {0.f, 0.f, 0.f, 0.f};
  f32x4 acc[4][4];
  for (int i = 0; i < 4; i++)
    for (int j = 0; j < 4; j++) acc[i][j] = z4;

  const int srow = lane >> 3, cpos = lane & 7;
  const int swz = (cpos ^ srow) * 8;
  const short* wg = Wb + (size_t)(m0 + w * 32 + srow) * 256 + swz;
  const short* xg = Xt + ((size_t)b * 1024 + n0 + w * 32 + srow) * 256 + swz;
  short* lA = &As[(w * 32) * 64];
  short* lB = &Bs[(w * 32) * 64];

  for (int k0 = 0; k0 < 256; k0 += 64) {
    __syncthreads();
#pragma unroll
    for (int qq = 0; qq < 4; ++qq) {
      load_lds16(wg + (size_t)qq * 8 * 256 + k0, lA + qq * 8 * 64);
      load_lds16(xg + (size_t)qq * 8 * 256 + k0, lB + qq * 8 * 64);
    }
    __syncthreads();
#pragma unroll
    for (int s = 0; s < 2; ++s) {
      const int cc = ((s * 4 + quad) ^ (l15 & 7)) * 8;
      short8 af[4], bfb[4];
      for (int i = 0; i < 4; i++) af[i] = *(const short8*)&As[(wm + i * 16 + l15) * 64 + cc];
      for (int j = 0; j < 4; j++) bfb[j] = *(const short8*)&Bs[(wn + j * 16 + l15) * 64 + cc];
      for (int i = 0; i < 4; i++)
        for (int j = 0; j < 4; j++) acc[i][j] = MFMA16(af[i], bfb[j], acc[i][j]);
    }
  }
  for (int i = 0; i < 4; i++) {
    int mi = m0 + wm + i * 16;
    int h = mi / 96;
    int rr = mi - h * 96;
    if (rr < 64) {  // q or k: [b,h,s,d]
      short* dst = (rr < 32) ? Qb : Kb;
      const float mul = (rr < 32) ? QSCALE : 1.0f;
      const int dbase = (rr & 31) + quad * 4;
      const size_t rowb = ((size_t)b * 8 + h) * 1024;
      for (int j = 0; j < 4; j++) {
        int n = n0 + wn + j * 16 + l15;
        union { unsigned u[2]; short4_ s; } uv;
        uv.u[0] = pk2bf(acc[i][j][0] * mul, acc[i][j][1] * mul);
        uv.u[1] = pk2bf(acc[i][j][2] * mul, acc[i][j][3] * mul);
        *(short4_*)(dst + (rowb + n) * 32 + dbase) = uv.s;
      }
    } else {  // v: [b,h,d,s]
      const int dv = (rr - 64) + quad * 4;
      const size_t vb = (((size_t)b * 8 + h) * 32 + dv) * 1024;
      for (int j = 0; j < 4; j++) {
        int n = n0 + wn + j * 16 + l15;
        for (int r = 0; r < 4; r++) Vb[vb + (size_t)r * 1024 + n] = f2bf(acc[i][j][r]);
      }
    }
  }
}

// ---------------------------------------------------------------------------
// Flash cross-attention, both branches. Grid (b=16, h=8, z=qt+4*br): the 4
// qt-blocks sharing one (b,h)'s K/V have linear stride 128 -> same XCD.
// Block = 256 queries; wave owns FOUR 16-q blocks (K-frag reads, V addressing
// and staging amortized 4x). 256-key LDS tiles via global_load_lds (XOR-
// swizzled). S^T=MFMA(A=K,B=Q); p=approx_exp2 (full-rate Schraudolph; errors
// cancel num/denom); P bf16-truncated (v_perm); l via ones-MFMA.
// ---------------------------------------------------------------------------
__global__ __launch_bounds__(256) void attn_kernel(char* __restrict__ ws) {
  const int b = blockIdx.x, h = blockIdx.y;
  const int qt = blockIdx.z & 3, br = blockIdx.z >> 2;
  // branch A output (br=0) uses Q from B, K/V from A; br=1 mirrored
  const short* Qb = (const short*)(ws + (br ? OFF_QBA : OFF_QBB));
  const short* Kb = (const short*)(ws + (br ? OFF_KBB : OFF_KBA));
  const short* Vb = Kb + 4194304;
  short* AO = (short*)(ws + (br ? OFF_AOB : OFF_AOA));
  const int t = threadIdx.x;
  const int w = t >> 6, lane = t & 63, l15 = lane & 15, quad = lane >> 4;
  const size_t hb = (size_t)(b * 8 + h);
  const f32x4 z4 = {0.f, 0.f, 0.f, 0.f};
  __shared__ short Ks[256 * 32];  // [sk][d], 16B-chunk col ^ ((sk>>1)&3)
  __shared__ short Vs[32 * 256];  // [dv][sk_loc], 16B-chunk col ^ (dv&15)

  const int q0 = qt * 256 + w * 64;
  short8 bq[4];
#pragma unroll
  for (int s = 0; s < 4; ++s)
    bq[s] = *(const short8*)(Qb + (hb * 1024 + q0 + s * 16 + l15) * 32 + quad * 8);
  const short* Kg = Kb + hb * 1024 * 32;
  const short* Vg = Vb + hb * 32 * 1024;

  short8 ones;
#pragma unroll
  for (int i = 0; i < 8; ++i) ones[i] = (short)0x3F80;  // bf16 1.0

  const int rk_off = lane >> 2;
  const int ck = lane & 3;
  const int rv_off = lane >> 5;
  const int cv = lane & 31;
  const int kread = l15 * 32 + ((quad ^ ((l15 >> 1) & 3)) * 8);

  f32x4 accO[4][2];  // [sq-block][dvt]
  f32x4 accL[4];
#pragma unroll
  for (int s = 0; s < 4; ++s) { accO[s][0] = z4; accO[s][1] = z4; accL[s] = z4; }

  for (int k0 = 0; k0 < 1024; k0 += 256) {
    __syncthreads();
    for (int p = 0; p < 4; ++p) {
      const int rk = (w * 4 + p) * 16 + rk_off;
      load_lds16(Kg + (size_t)(k0 + rk) * 32 + ((ck ^ ((rk >> 1) & 3)) * 8),
                 &Ks[(w * 4 + p) * 512]);
      const int rv = (w * 4 + p) * 2 + rv_off;
      load_lds16(Vg + (size_t)rv * 1024 + k0 + ((cv ^ (rv & 15)) * 8),
                 &Vs[(w * 4 + p) * 512]);
    }
    __syncthreads();

#pragma unroll
    for (int pr = 0; pr < 8; ++pr) {
      const short8 ak0 = *(const short8*)&Ks[(2 * pr) * 512 + kread];
      const short8 ak1 = *(const short8*)&Ks[(2 * pr + 1) * 512 + kread];
      // V operand (shared across the 4 sq-blocks)
      const int cg = pr * 4 + (quad >> 1);
      const int so = (quad & 1) * 4;
      union { short8 s; short4_ hh[2]; } bv[2];
#pragma unroll
      for (int dvt = 0; dvt < 2; ++dvt) {
        const int dvrow = (dvt * 16 + l15) * 256;
        bv[dvt].hh[0] = *(const short4_*)&Vs[dvrow + ((cg ^ l15) * 8) + so];
        bv[dvt].hh[1] = *(const short4_*)&Vs[dvrow + (((cg + 2) ^ l15) * 8) + so];
      }
#pragma unroll
      for (int s = 0; s < 4; ++s) {
        f32x4 st0 = MFMA16(ak0, bq[s], z4);
        f32x4 st1 = MFMA16(ak1, bq[s], z4);
        union { short8 s8; uint4_ u; } apv;
        float p0 = approx_exp2(st0[0]), p1 = approx_exp2(st0[1]);
        float p2 = approx_exp2(st0[2]), p3 = approx_exp2(st0[3]);
        float p4 = approx_exp2(st1[0]), p5 = approx_exp2(st1[1]);
        float p6 = approx_exp2(st1[2]), p7 = approx_exp2(st1[3]);
        apv.u[0] = pktrunc(p0, p1); apv.u[1] = pktrunc(p2, p3);
        apv.u[2] = pktrunc(p4, p5); apv.u[3] = pktrunc(p6, p7);
        accO[s][0] = MFMA16(apv.s8, bv[0].s, accO[s][0]);
        accO[s][1] = MFMA16(apv.s8, bv[1].s, accO[s][1]);
        accL[s] = MFMA16(apv.s8, ones, accL[s]);
      }
    }
  }

#pragma unroll
  for (int s = 0; s < 4; ++s) {
    for (int r = 0; r < 4; r++) {
      float inv = 1.0f / accL[s][r];
      int sq = q0 + s * 16 + quad * 4 + r;
      short* orow = AO + ((size_t)b * 1024 + sq) * 256 + h * 32 + l15;
      orow[0] = f2bf(accO[s][0][r] * inv);
      orow[16] = f2bf(accO[s][1][r] * inv);
    }
  }
}

// ---------------------------------------------------------------------------
// Output GEMM, both branches: out[b,m,n] = sum_k Wob[m,k]*ao[b,n,k] + bias[m]
// + norm[b,m,n]. Grid (mt=2, nt=8, z=b+16*br).
// ---------------------------------------------------------------------------
__global__ __launch_bounds__(256) void gemm_out_kernel(char* __restrict__ ws,
                                                       const float* __restrict__ boutA,
                                                       const float* __restrict__ boutB,
                                                       float* __restrict__ outbase) {
  const int m0 = blockIdx.x * 128, n0 = blockIdx.y * 128;
  const int b = blockIdx.z & 15, br = blockIdx.z >> 4;
  const short* Wob = (const short*)(ws + (br ? OFF_WOB : OFF_WOA));
  const short* ao = (const short*)(ws + (br ? OFF_AOB : OFF_AOA));
  const float* bias = br ? boutB : boutA;
  const short* Xt = (const short*)(ws + (br ? OFF_XTB : OFF_XTA));
  float* out = outbase + (br ? 4194304 : 0);
  const int t = threadIdx.x;
  __shared__ short smem[128 * 64 * 2];
  short* As = smem;
  short* Bs = smem + 128 * 64;
  const int w = t >> 6, lane = t & 63, l15 = lane & 15, quad = lane >> 4;
  const int wm = (w >> 1) * 64, wn = (w & 1) * 64;
  const f32x4 z4 = {0.f, 0.f, 0.f, 0.f};
  f32x4 acc[4][4];
  for (int i = 0; i < 4; i++)
    for (int j = 0; j < 4; j++) acc[i][j] = z4;

  const int srow = lane >> 3, cpos = lane & 7;
  const int swz = (cpos ^ srow) * 8;
  const short* wg = Wob + (size_t)(m0 + w * 32 + srow) * 256 + swz;
  const short* xg = ao + ((size_t)b * 1024 + n0 + w * 32 + srow) * 256 + swz;
  short* lA = &As[(w * 32) * 64];
  short* lB = &Bs[(w * 32) * 64];

  for (int k0 = 0; k0 < 256; k0 += 64) {
    __syncthreads();
#pragma unroll
    for (int qq = 0; qq < 4; ++qq) {
      load_lds16(wg + (size_t)qq * 8 * 256 + k0, lA + qq * 8 * 64);
      load_lds16(xg + (size_t)qq * 8 * 256 + k0, lB + qq * 8 * 64);
    }
    __syncthreads();
#pragma unroll
    for (int s = 0; s < 2; ++s) {
      const int cc = ((s * 4 + quad) ^ (l15 & 7)) * 8;
      short8 af[4], bfb[4];
      for (int i = 0; i < 4; i++) af[i] = *(const short8*)&As[(wm + i * 16 + l15) * 64 + cc];
      for (int j = 0; j < 4; j++) bfb[j] = *(const short8*)&Bs[(wn + j * 16 + l15) * 64 + cc];
      for (int i = 0; i < 4; i++)
        for (int j = 0; j < 4; j++) acc[i][j] = MFMA16(af[i], bfb[j], acc[i][j]);
    }
  }

  __syncthreads();
  {
    const int rrow = lane >> 4, rc = lane & 15;
    for (int qq = 0; qq < 8; ++qq) {
      int row = w * 32 + qq * 4 + rrow;
      load_lds16(Xt + ((size_t)b * 1024 + n0 + row) * 256 + m0 + ((rc ^ (row & 15)) * 8),
                 &smem[(w * 32 + qq * 4) * 128]);
    }
  }
  __syncthreads();

  for (int i = 0; i < 4; i++)
    for (int j = 0; j < 4; j++) {
      int m = m0 + wm + i * 16 + quad * 4;
      int nl = wn + j * 16 + l15;
      int n = n0 + nl;
      size_t off = ((size_t)b * 256 + m) * 1024 + n;
      const int chunk = (wm >> 3) + i * 2 + (quad >> 1);
      short4_ rv = *(const short4_*)&smem[nl * 128 + ((chunk ^ (nl & 15)) * 8) + (quad & 1) * 4];
      for (int r = 0; r < 4; r++)
        out[off + (size_t)r * 1024] = acc[i][j][r] + bias[m + r] + bf2f(rv[r]);
    }
}

// ---------------------------------------------------------------------------
extern "C" void kernel_launch(void* const* d_in, const int* in_sizes, int n_in,
                              void* d_out, int out_size, void* d_ws, size_t ws_size,
                              hipStream_t stream) {
  const float* xA = (const float*)d_in[0];
  const float* xB = (const float*)d_in[1];
  const float* gA = (const float*)d_in[2];
  const float* bA = (const float*)d_in[3];
  const float* gB = (const float*)d_in[4];
  const float* bB = (const float*)d_in[5];
  const float* WqkvA = (const float*)d_in[6];
  const float* WqkvB = (const float*)d_in[7];
  const float* WoutA = (const float*)d_in[8];
  const float* boutA = (const float*)d_in[9];
  const float* WoutB = (const float*)d_in[10];
  const float* boutB = (const float*)d_in[11];
  float* out = (float*)d_out;
  char* ws = (char*)d_ws;

  prep_kernel<<<768, 256, 0, stream>>>(xA, xB, gA, bA, gB, bB,
                                       WqkvA, WqkvB, WoutA, WoutB, ws);
  gemm_qkv_kernel<<<dim3(8, 6, 32), 256, 0, stream>>>(ws);
  attn_kernel<<<dim3(16, 8, 8), 256, 0, stream>>>(ws);
  gemm_out_kernel<<<dim3(2, 8, 32), 256, 0, stream>>>(ws, boutA, boutB, out);
}